// Round 17
// baseline (204.867 us; speedup 1.0000x reference)
//
#include <hip/hip_runtime.h>
#include <hip/hip_bf16.h>
#include <math.h>

#define EMBED 384
#define HEADS 6
#define HD    64
#define NF    32
#define SEQ   1025
#define SEQP  1088   // padded key stride for Vt (17*64)
#define BATCH 16
#define MTOT  (BATCH*SEQ)   // 16400
#define NCHUNK 17
#define LSTRIDE 72   // attn K LDS row stride (elems)
#define VSTR   68    // attn V LDS row stride (elems): 136B -> conflict-free b64 reads
#define TSTR   66    // qkv epilogue transpose tile stride (2-way max conflicts)

// fused prep kernel block ranges (x->bf16 pass eliminated; qkv converts A)
#define NB_TW  144                   // 6*6*4
#define NB_RT  769                   // ceil(SEQ*HEADS*NF/256)
#define NB_VF  192                   // vt tail zero-fill: 96*64 rows x 64 cols /8 /256

typedef __bf16 bf16x8 __attribute__((ext_vector_type(8)));
typedef __bf16 bf16x4 __attribute__((ext_vector_type(4)));
typedef float  f32x4  __attribute__((ext_vector_type(4)));
typedef short  s16x4  __attribute__((ext_vector_type(4)));

#define MFMA_BF16(A,B,C) __builtin_amdgcn_mfma_f32_16x16x32_bf16((A),(B),(C),0,0,0)
// K=16 bf16 MFMA (v_mfma_f32_16x16x16_bf16 on gfx950); A/B = short4 of bf16 bits
#define MFMA16(A,B,C) __builtin_amdgcn_mfma_f32_16x16x16bf16_1k((A),(B),(C),0,0,0)

// async global->LDS, 16B per lane: per-lane global src, wave-uniform LDS dest
#define GLL16(gp, lp) __builtin_amdgcn_global_load_lds( \
    (const __attribute__((address_space(1))) void*)(gp), \
    (__attribute__((address_space(3))) void*)(lp), 16, 0, 0)

__device__ __forceinline__ __bf16 f2bf(float f){
    __hip_bfloat16 h = __float2bfloat16(f);
    return *reinterpret_cast<__bf16*>(&h);
}
__device__ __forceinline__ short bfbits(float f){
    __hip_bfloat16 h = __float2bfloat16(f);
    return *reinterpret_cast<short*>(&h);
}

// fp32 erfinv (Giles 2010)
__device__ __forceinline__ float erfinv_f(float x){
    float w = -log1pf(-x*x);
    float p;
    if (w < 5.0f){
        w -= 2.5f;
        p = 2.81022636e-08f;
        p = fmaf(p, w, 3.43273939e-07f);
        p = fmaf(p, w, -3.5233877e-06f);
        p = fmaf(p, w, -4.39150654e-06f);
        p = fmaf(p, w, 0.00021858087f);
        p = fmaf(p, w, -0.00125372503f);
        p = fmaf(p, w, -0.00417768164f);
        p = fmaf(p, w, 0.246640727f);
        p = fmaf(p, w, 1.50140941f);
    } else {
        w = sqrtf(w) - 3.0f;
        p = -0.000200214257f;
        p = fmaf(p, w, 0.000100950558f);
        p = fmaf(p, w, 0.00134934322f);
        p = fmaf(p, w, -0.00367342844f);
        p = fmaf(p, w, 0.00573950773f);
        p = fmaf(p, w, -0.0076224613f);
        p = fmaf(p, w, 0.00943887047f);
        p = fmaf(p, w, 1.00167406f);
        p = fmaf(p, w, 2.83297682f);
    }
    return p * x;
}

// -------- fused prep: W transpose | rope tables | vt tail fill ----
__global__ __launch_bounds__(256) void prep_kernel(
    const float* __restrict__ Wq, const float* __restrict__ Wk,
    const float* __restrict__ Wv, const float* __restrict__ Wo,
    __hip_bfloat16* __restrict__ Wt,
    float* __restrict__ cos_t, float* __restrict__ sin_t,
    __hip_bfloat16* __restrict__ vt)
{
    __shared__ float tile[64][65];
    const int bid = blockIdx.x;
    const int tid = threadIdx.x;

    if (bid < NB_TW){
        // ---- weight transpose: W fp32 [k][n] -> Wt bf16 [mat][n][k] ----
        int idx = bid;                          // 0..143
        const int mat = idx / 36;
        const int rem = idx % 36;
        const int kx = rem / 6, ny = rem % 6;
        const float* W = (mat==0)?Wq:(mat==1)?Wk:(mat==2)?Wv:Wo;
        const int k0 = kx*64, n0 = ny*64;
        const int c = tid & 63, rq = tid >> 6;
        #pragma unroll
        for (int i = 0; i < 16; ++i){
            int row = rq*16 + i;
            tile[row][c] = W[(size_t)(k0+row)*EMBED + n0 + c];
        }
        __syncthreads();
        #pragma unroll
        for (int i = 0; i < 16; ++i){
            int nr = rq*16 + i;
            Wt[((size_t)mat*EMBED + n0 + nr)*EMBED + k0 + c] = __float2bfloat16(tile[c][nr]);
        }
        return;
    }
    if (bid < NB_TW + NB_RT){
        // ---- rope tables ----
        int idx = (bid - NB_TW)*256 + tid;
        if (idx >= SEQ*HEADS*NF) return;
        int f  = idx & (NF-1);
        int hf = idx / NF;
        int h  = hf % HEADS;
        int s  = hf / HEADS;

        double xd = 2.0;
        #pragma unroll
        for (int it = 0; it < 10; ++it) xd = cbrt(1.0 + xd);
        float a1 = (float)(1.0 / xd);
        float a2 = a1 * a1;

        float fi = (float)(h*NF + f + 1);
        float z1 = fmodf(fi * a1, 1.0f);
        float z2 = fmodf(fi * a2, 1.0f);
        float d1 = erfinv_f(2.0f*z1 - 1.0f);
        float d2 = erfinv_f(2.0f*z2 - 1.0f);
        float inv = 1.0f / sqrtf(d1*d1 + d2*d2);
        d1 *= inv; d2 *= inv;

        float omega = 0.1f * powf(10000.0f, (float)f / 31.0f);
        float fx = d1 * omega, fy = d2 * omega;

        float cx = 0.0f, cy = 0.0f;
        if (s > 0){
            int pi = s - 1;
            cx = (float)(pi & 31) / 31.0f * 2.0f - 1.0f;
            cy = (float)(pi >> 5) / 31.0f * 2.0f - 1.0f;
        }
        float theta = fx*cx + fy*cy;
        float sv, cv;
        sincosf(theta, &sv, &cv);
        cos_t[idx] = cv;
        sin_t[idx] = sv;
        return;
    }
    // ---- vt tail zero-fill: cols 1024..1087 of all 96*64 rows ----
    {
        int g = (bid - NB_TW - NB_RT)*256 + tid;   // < 49152 exact
        int row = g >> 3, sg = g & 7;
        bf16x8 z = {};
        *reinterpret_cast<bf16x8*>(reinterpret_cast<__bf16*>(vt)
            + (size_t)row*SEQP + 1024 + sg*8) = z;
    }
}

// QKV: one big GEMM x[16400x384](fp32) @ Wt[1152x384]^T, 128x128 tiles.
// grid (129, 9), block 256 (4 waves, 2x2). Wave = 64 rows x one head's 64 cols.
// A staged from fp32 source via regs (fused x->bf16 conversion, x2b pass
// eliminated); B via global_load_lds width=16. Double-buffered, one barrier.
// Epilogue: RoPE for q/k; V^T written directly via LDS transpose.
__global__ __launch_bounds__(256, 3) void qkv_rope_kernel(
    const float* __restrict__ x_,
    const __hip_bfloat16* __restrict__ Wt,
    const float* __restrict__ cos_t,
    const float* __restrict__ sin_t,
    __hip_bfloat16* __restrict__ qbuf,
    __hip_bfloat16* __restrict__ kbuf,
    __hip_bfloat16* __restrict__ vtbuf)
{
    __shared__ __align__(16) __bf16 smem[16384];   // 32KB: xs dbuf + bt dbuf
    const int tid = threadIdx.x;
    const int m0 = blockIdx.x * 128;
    const int j  = blockIdx.y;
    const __bf16* wt = reinterpret_cast<const __bf16*>(Wt);
    __bf16* vtb = reinterpret_cast<__bf16*>(vtbuf);

    const int w = tid >> 6;
    const int lane = tid & 63;
    const int quad = lane >> 4, low = lane & 15;
    const int rg = lane >> 2, cg = lane & 3;   // B: 16 rows x 4 granules/chunk

    // B staging (gload_lds): wave w stages chunks w*2, w*2+1 (16 rows each)
    int brow[2], loff[2];
    #pragma unroll
    for (int i = 0; i < 2; ++i){
        int row = (w*2 + i)*16 + rg;
        brow[i] = j*128 + row;          // < 1152 always
        loff[i] = (w*2 + i)*1024;       // bytes: 16 rows x 64B
    }
    // A staging (reg + convert): granule g = tid + i*256; row=g>>2, kc=g&3
    int ar_row[2], ar_kc[2], aoffe[2];
    #pragma unroll
    for (int i = 0; i < 2; ++i){
        int g = tid + i*256;
        int row = g >> 2, kc = g & 3;
        int am = m0 + row; if (am > MTOT-1) am = MTOT-1;
        ar_row[i] = am; ar_kc[i] = kc;
        aoffe[i] = row*32 + kc*8;       // elems in [128][32] tile
    }

    // prologue: stage tile 0 into buffer 0 (xs at smem[0], bt at smem[8192])
    {
        float4 a4[2][2];
        #pragma unroll
        for (int i = 0; i < 2; ++i){
            const float* src = x_ + (size_t)ar_row[i]*EMBED + ar_kc[i]*8;
            a4[i][0] = *reinterpret_cast<const float4*>(src);
            a4[i][1] = *reinterpret_cast<const float4*>(src + 4);
            GLL16(wt + (size_t)brow[i]*EMBED + cg*8, (char*)(smem + 8192) + loff[i]);
        }
        #pragma unroll
        for (int i = 0; i < 2; ++i){
            bf16x8 v;
            v[0]=f2bf(a4[i][0].x); v[1]=f2bf(a4[i][0].y); v[2]=f2bf(a4[i][0].z); v[3]=f2bf(a4[i][0].w);
            v[4]=f2bf(a4[i][1].x); v[5]=f2bf(a4[i][1].y); v[6]=f2bf(a4[i][1].z); v[7]=f2bf(a4[i][1].w);
            *reinterpret_cast<bf16x8*>(&smem[aoffe[i]]) = v;
        }
    }
    __syncthreads();

    const int mh = w >> 1, nh = w & 1;
    const int mw0 = m0 + mh*64;

    f32x4 acc[4][4] = {};
    for (int kb = 0; kb < 12; ++kb){
        const int cur = kb & 1;
        const __bf16* xcur = smem + cur*4096;
        const __bf16* bcur = smem + 8192 + cur*4096;
        float4 a4[2][2];
        // issue tile k+1's loads (B async to LDS, A fp32 to regs) early
        if (kb < 11){
            const int k1 = (kb+1)*32;
            #pragma unroll
            for (int i = 0; i < 2; ++i){
                GLL16(wt + (size_t)brow[i]*EMBED + k1 + cg*8,
                      (char*)(smem + 8192 + (cur^1)*4096) + loff[i]);
                const float* src = x_ + (size_t)ar_row[i]*EMBED + k1 + ar_kc[i]*8;
                a4[i][0] = *reinterpret_cast<const float4*>(src);
                a4[i][1] = *reinterpret_cast<const float4*>(src + 4);
            }
        }
        bf16x8 af[4], bfr[4];
        #pragma unroll
        for (int mt = 0; mt < 4; ++mt)
            af[mt] = *reinterpret_cast<const bf16x8*>(&xcur[(mh*64 + mt*16 + low)*32 + quad*8]);
        #pragma unroll
        for (int t = 0; t < 4; ++t)
            bfr[t] = *reinterpret_cast<const bf16x8*>(&bcur[(nh*64 + t*16 + low)*32 + quad*8]);
        #pragma unroll
        for (int t = 0; t < 4; ++t)
            #pragma unroll
            for (int mt = 0; mt < 4; ++mt)
                acc[mt][t] = MFMA_BF16(af[mt], bfr[t], acc[mt][t]);
        if (kb < 11){
            // write-late: convert + store A(k+1) to the alternate buffer
            __bf16* xnxt = smem + (cur^1)*4096;
            #pragma unroll
            for (int i = 0; i < 2; ++i){
                bf16x8 v;
                v[0]=f2bf(a4[i][0].x); v[1]=f2bf(a4[i][0].y); v[2]=f2bf(a4[i][0].z); v[3]=f2bf(a4[i][0].w);
                v[4]=f2bf(a4[i][1].x); v[5]=f2bf(a4[i][1].y); v[6]=f2bf(a4[i][1].z); v[7]=f2bf(a4[i][1].w);
                *reinterpret_cast<bf16x8*>(&xnxt[aoffe[i]]) = v;
            }
            __syncthreads();   // drains vmcnt(0): B tile k+1 landed; orders ds
        }
    }

    const int n64 = j*2 + nh;           // 0..17
    const int mat = n64 / 6;            // j-uniform (2j and 2j+1 share mat)
    const int h   = n64 % 6;

    if (mat == 2){
        // ---- V^T direct store via LDS transpose (block-uniform branch) ----
        __syncthreads();                // main-loop LDS reads done
        const int d8 = lane >> 3, sg = lane & 7;
        const int m0c = mw0 + sg*8;
        const int b0 = m0c / SEQ;
        const int s0 = m0c - b0*SEQ;
        const bool fast = (m0c + 7 < MTOT) && (s0 + 7 < SEQ);
        #pragma unroll
        for (int ph = 0; ph < 2; ++ph){
            if (mh == ph){
                __bf16* tl = smem + nh*4608;       // 64 x TSTR(66)
                #pragma unroll
                for (int mt = 0; mt < 4; ++mt)
                    #pragma unroll
                    for (int t = 0; t < 4; ++t)
                        #pragma unroll
                        for (int r = 0; r < 4; ++r)
                            tl[(mt*16 + quad*4 + r)*TSTR + t*16 + low] = f2bf(acc[mt][t][r]);
            }
            __syncthreads();
            if (mh == ph){
                __bf16* tl = smem + nh*4608;
                #pragma unroll
                for (int db = 0; db < 8; ++db){
                    const int d = db*8 + d8;
                    if (fast){
                        bf16x8 val;
                        #pragma unroll
                        for (int e = 0; e < 8; ++e) val[e] = tl[(sg*8+e)*TSTR + d];
                        *reinterpret_cast<bf16x8*>(
                            vtb + ((size_t)(b0*HEADS + h)*HD + d)*SEQP + s0) = val;
                    } else {
                        #pragma unroll
                        for (int e = 0; e < 8; ++e){
                            int m = m0c + e;
                            if (m < MTOT){
                                int bb = m / SEQ, ss = m - bb*SEQ;
                                vtb[((size_t)(bb*HEADS + h)*HD + d)*SEQP + ss] =
                                    tl[(sg*8+e)*TSTR + d];
                            }
                        }
                    }
                }
            }
            __syncthreads();
        }
    } else {
        __hip_bfloat16* ob = (mat == 0) ? qbuf : kbuf;
        const float qs_ = (mat == 0) ? 0.125f : 1.0f;
        #pragma unroll
        for (int mt = 0; mt < 4; ++mt)
            #pragma unroll
            for (int t = 0; t < 2; ++t)
                #pragma unroll
                for (int r = 0; r < 4; ++r){
                    int m = mw0 + mt*16 + quad*4 + r;
                    if (m < MTOT){
                        int b = m / SEQ, s = m % SEQ;
                        int f = t*16 + low;
                        float cv = cos_t[(s*HEADS + h)*NF + f];
                        float sv = sin_t[(s*HEADS + h)*NF + f];
                        float x1 = acc[mt][t][r];
                        float y1 = acc[mt][t+2][r];
                        size_t base = ((size_t)(b*HEADS + h)*SEQ + s)*HD;
                        ob[base + f]      = __float2bfloat16((x1*cv - y1*sv)*qs_);
                        ob[base + NF + f] = __float2bfloat16((x1*sv + y1*cv)*qs_);
                    }
                }
    }
}

// Flash attention, fixed-base softmax (no running max: scores bounded ~|5|).
// S^T = K.Q^T (qrow in-lane). PV = P.V via 16x16x16 MFMA with P entirely
// in registers. [round-12 exact, measured 54.4us]
__global__ __launch_bounds__(256, 4) void attn_kernel(
    const __hip_bfloat16* __restrict__ qbuf,
    const __hip_bfloat16* __restrict__ kbuf,
    const __hip_bfloat16* __restrict__ vtbuf,
    __hip_bfloat16* __restrict__ aout)
{
    __shared__ __align__(16) __bf16 kls[64*LSTRIDE];    // [key][feat]
    __shared__ __align__(16) __bf16 vls[64*VSTR];       // [d][key], 136B stride
    const int tid  = threadIdx.x;
    const int w    = tid >> 6;
    const int lane = tid & 63;
    const int quad = lane >> 4, low = lane & 15;
    const int id = blockIdx.x;
    const int bh = id % 96;
    const int qt = id / 96;
    const int b = bh / HEADS, h = bh % HEADS;
    const __bf16* qb = reinterpret_cast<const __bf16*>(qbuf);
    const __bf16* kb = reinterpret_cast<const __bf16*>(kbuf);
    const __bf16* vt = reinterpret_cast<const __bf16*>(vtbuf);
    const size_t base   = (size_t)bh * SEQ * HD;
    const size_t vtbase = (size_t)bh * HD * SEQP;
    const int q0 = qt*128 + w*32;

    int srow[2], sgk[2], soffk[2], soffv[2];
    #pragma unroll
    for (int i = 0; i < 2; ++i){
        int ch = tid + i*256;
        srow[i] = ch >> 3; sgk[i] = ch & 7;
        soffk[i] = srow[i]*LSTRIDE + sgk[i]*8;
        soffv[i] = srow[i]*VSTR    + sgk[i]*8;
    }

    bf16x8 bq[2][2];
    #pragma unroll
    for (int nt = 0; nt < 2; ++nt){
        int qs = q0 + nt*16 + low; if (qs > SEQ-1) qs = SEQ-1;
        #pragma unroll
        for (int ks = 0; ks < 2; ++ks)
            bq[nt][ks] = *reinterpret_cast<const bf16x8*>(qb + base + (size_t)qs*HD + ks*32 + quad*8);
    }

    bf16x8 kr[2], vr[2];
    #pragma unroll
    for (int i = 0; i < 2; ++i){
        int kk = srow[i]; if (kk > SEQ-1) kk = SEQ-1;
        kr[i] = *reinterpret_cast<const bf16x8*>(kb + base + (size_t)kk*HD + sgk[i]*8);
        vr[i] = *reinterpret_cast<const bf16x8*>(vt + vtbase + (size_t)srow[i]*SEQP + sgk[i]*8);
    }

    f32x4 o[2][4] = {};          // o[nt][dt]: row=q (quad*4+r), col=d (dt*16+low)
    float l_i[2] = {0.f, 0.f};

    for (int c = 0; c < NCHUNK; ++c){
        const int c0 = c*64;
        __syncthreads();
        #pragma unroll
        for (int i = 0; i < 2; ++i){
            *reinterpret_cast<bf16x8*>(&kls[soffk[i]]) = kr[i];
            bf16x4 vlo = __builtin_shufflevector(vr[i], vr[i], 0,1,2,3);
            bf16x4 vhi = __builtin_shufflevector(vr[i], vr[i], 4,5,6,7);
            *reinterpret_cast<bf16x4*>(&vls[soffv[i]])     = vlo;
            *reinterpret_cast<bf16x4*>(&vls[soffv[i] + 4]) = vhi;
        }
        __syncthreads();
        if (c + 1 < NCHUNK){
            const int c1 = c0 + 64;
            #pragma unroll
            for (int i = 0; i < 2; ++i){
                int kk = c1 + srow[i]; if (kk > SEQ-1) kk = SEQ-1;
                kr[i] = *reinterpret_cast<const bf16x8*>(kb + base + (size_t)kk*HD + sgk[i]*8);
                vr[i] = *reinterpret_cast<const bf16x8*>(vt + vtbase + (size_t)srow[i]*SEQP + c1 + sgk[i]*8);
            }
        }
        f32x4 st[4][2] = {};
        #pragma unroll
        for (int kt = 0; kt < 4; ++kt)
            #pragma unroll
            for (int ks = 0; ks < 2; ++ks){
                bf16x8 ak = *reinterpret_cast<const bf16x8*>(&kls[(kt*16 + low)*LSTRIDE + ks*32 + quad*8]);
                #pragma unroll
                for (int nt = 0; nt < 2; ++nt)
                    st[kt][nt] = MFMA_BF16(ak, bq[nt][ks], st[kt][nt]);
            }
        if (c0 + 64 > SEQ){
            #pragma unroll
            for (int kt = 0; kt < 4; ++kt)
                #pragma unroll
                for (int r = 0; r < 4; ++r){
                    int key = c0 + kt*16 + quad*4 + r;
                    if (key >= SEQ){ st[kt][0][r] = -1e30f; st[kt][1][r] = -1e30f; }
                }
        }
        // exp + in-lane l partial + pack P to bf16 A-fragments (in-register)
        s16x4 pa[4][2];
        #pragma unroll
        for (int nt = 0; nt < 2; ++nt)
            #pragma unroll
            for (int kt = 0; kt < 4; ++kt)
                #pragma unroll
                for (int r = 0; r < 4; ++r){
                    float p = __expf(st[kt][nt][r]);
                    l_i[nt] += p;
                    pa[kt][nt][r] = bfbits(p);
                }
        // O += P.V, A=P in-register, B=V from vls (conflict-free b64 reads)
        #pragma unroll
        for (int kt = 0; kt < 4; ++kt)
            #pragma unroll
            for (int dt = 0; dt < 4; ++dt){
                const s16x4 bv = *reinterpret_cast<const s16x4*>(&vls[(dt*16 + low)*VSTR + kt*16 + quad*4]);
                #pragma unroll
                for (int nt = 0; nt < 2; ++nt)
                    o[nt][dt] = MFMA16(pa[kt][nt], bv, o[nt][dt]);
            }
    }

    // reduce l across quads (lanes sharing 'low'), redistribute to output rows
    #pragma unroll
    for (int nt = 0; nt < 2; ++nt){
        l_i[nt] += __shfl_xor(l_i[nt], 16, 64);
        l_i[nt] += __shfl_xor(l_i[nt], 32, 64);
    }
    float lq[2][4];
    #pragma unroll
    for (int nt = 0; nt < 2; ++nt)
        #pragma unroll
        for (int r = 0; r < 4; ++r)
            lq[nt][r] = __shfl(l_i[nt], quad*4 + r, 64);

    #pragma unroll
    for (int nt = 0; nt < 2; ++nt)
        #pragma unroll
        for (int r = 0; r < 4; ++r){
            int s = q0 + nt*16 + quad*4 + r;
            if (s < SEQ){
                float inv = 1.0f / lq[nt][r];
                __hip_bfloat16* dst = aout + ((size_t)b*SEQ + s)*EMBED + h*HD;
                #pragma unroll
                for (int dt = 0; dt < 4; ++dt)
                    dst[dt*16 + low] = __float2bfloat16(o[nt][dt][r]*inv);
            }
        }
}

// out = attn @ Wo + bo. 64x128 tiles, 128 threads (2 waves x 64x64),
// grid (257, 3) = 771 blocks ~= 3.0/CU. m97-style double-buffered pipeline.
__global__ __launch_bounds__(128) void outproj_kernel(
    const __hip_bfloat16* __restrict__ a,
    const __hip_bfloat16* __restrict__ Wt,
    const float* __restrict__ bo,
    float* __restrict__ out)
{
    __shared__ __align__(16) __bf16 xs[2][64*32];
    __shared__ __align__(16) __bf16 bt[2][128*32];
    const int tid = threadIdx.x;          // 0..127
    const int m0 = blockIdx.x * 64;
    const int j  = blockIdx.y;
    const __bf16* ab = reinterpret_cast<const __bf16*>(a);
    const __bf16* wt = reinterpret_cast<const __bf16*>(Wt) + (size_t)3*EMBED*EMBED;

    const int w = tid >> 6;               // 0..1
    const int lane = tid & 63;
    const int quad = lane >> 4, low = lane & 15;
    const int rg = lane >> 2, cg = lane & 3;

    // A: 4 chunks of 16 rows; wave w stages chunks w*2, w*2+1
    int arow[2], aoff[2];
    #pragma unroll
    for (int i = 0; i < 2; ++i){
        int row = (w*2 + i)*16 + rg;
        int am = m0 + row; if (am > MTOT-1) am = MTOT-1;
        arow[i] = am;
        aoff[i] = (w*2 + i)*1024;
    }
    // B: 8 chunks of 16 rows; wave w stages chunks w*4 .. w*4+3
    int brow[4], boff[4];
    #pragma unroll
    for (int i = 0; i < 4; ++i){
        int row = (w*4 + i)*16 + rg;
        brow[i] = j*128 + row;
        boff[i] = (w*4 + i)*1024;
    }

    // prologue: stage tile 0 into buffer 0
    #pragma unroll
    for (int i = 0; i < 2; ++i)
        GLL16(ab + (size_t)arow[i]*EMBED + cg*8, (char*)xs[0] + aoff[i]);
    #pragma unroll
    for (int i = 0; i < 4; ++i)
        GLL16(wt + (size_t)brow[i]*EMBED + cg*8, (char*)bt[0] + boff[i]);
    __syncthreads();

    f32x4 acc[4][4] = {};
    for (int kb = 0; kb < 12; ++kb){
        const int cur = kb & 1;
        if (kb < 11){
            const int k1 = (kb+1)*32;
            #pragma unroll
            for (int i = 0; i < 2; ++i)
                GLL16(ab + (size_t)arow[i]*EMBED + k1 + cg*8, (char*)xs[cur^1] + aoff[i]);
            #pragma unroll
            for (int i = 0; i < 4; ++i)
                GLL16(wt + (size_t)brow[i]*EMBED + k1 + cg*8, (char*)bt[cur^1] + boff[i]);
        }
        bf16x8 af[4], bfr[4];
        #pragma unroll
        for (int mt = 0; mt < 4; ++mt)
            af[mt] = *reinterpret_cast<const bf16x8*>(&xs[cur][(mt*16 + low)*32 + quad*8]);
        #pragma unroll
        for (int t = 0; t < 4; ++t)
            bfr[t] = *reinterpret_cast<const bf16x8*>(&bt[cur][(w*64 + t*16 + low)*32 + quad*8]);
        #pragma unroll
        for (int t = 0; t < 4; ++t)
            #pragma unroll
            for (int mt = 0; mt < 4; ++mt)
                acc[mt][t] = MFMA_BF16(af[mt], bfr[t], acc[mt][t]);
        if (kb < 11) __syncthreads();
    }

    #pragma unroll
    for (int t = 0; t < 4; ++t){
        const int n = j*128 + w*64 + t*16 + low;
        const float bias = bo[n];
        #pragma unroll
        for (int mt = 0; mt < 4; ++mt)
            #pragma unroll
            for (int r = 0; r < 4; ++r){
                const int m = m0 + mt*16 + quad*4 + r;
                if (m < MTOT) out[(size_t)m*EMBED + n] = acc[mt][t][r] + bias;
            }
    }
}

extern "C" void kernel_launch(void* const* d_in, const int* in_sizes, int n_in,
                              void* d_out, int out_size, void* d_ws, size_t ws_size,
                              hipStream_t stream)
{
    const float* x  = (const float*)d_in[0];
    const float* Wq = (const float*)d_in[1];
    const float* Wk = (const float*)d_in[2];
    const float* Wv = (const float*)d_in[3];
    const float* Wo = (const float*)d_in[4];
    const float* bo = (const float*)d_in[5];
    float* out = (float*)d_out;

    const size_t NE = (size_t)MTOT * EMBED;                 // 6,297,600
    const size_t VT = (size_t)BATCH*HEADS*HD*SEQP;          // padded V^T elems
    char* ws = (char*)d_ws;
    size_t off = 0;
    __hip_bfloat16* qbuf = (__hip_bfloat16*)(ws + off); off += 2*NE;
    __hip_bfloat16* kbuf = (__hip_bfloat16*)(ws + off); off += 2*NE;
    __hip_bfloat16* abuf = (__hip_bfloat16*)(ws + off); off += 2*NE;
    __hip_bfloat16* vt   = (__hip_bfloat16*)(ws + off); off += 2*VT;
    __hip_bfloat16* Wt   = (__hip_bfloat16*)(ws + off); off += (size_t)4*EMBED*EMBED*2;
    float* cos_t = (float*)(ws + off); off += (size_t)SEQ*HEADS*NF*4;
    float* sin_t = (float*)(ws + off); off += (size_t)SEQ*HEADS*NF*4;

    prep_kernel<<<dim3(NB_TW + NB_RT + NB_VF), dim3(256), 0, stream>>>(
        Wq, Wk, Wv, Wo, Wt, cos_t, sin_t, vt);
    qkv_rope_kernel<<<dim3((MTOT + 127)/128, 9), dim3(256), 0, stream>>>(x, Wt, cos_t, sin_t, qbuf, kbuf, vt);
    attn_kernel<<<dim3(864), dim3(256), 0, stream>>>(qbuf, kbuf, vt, abuf);
    outproj_kernel<<<dim3((MTOT + 63)/64, 3), dim3(128), 0, stream>>>(abuf, Wt, bo, out);
}

// Round 18
// 202.364 us; speedup vs baseline: 1.0124x; 1.0124x over previous
//
#include <hip/hip_runtime.h>
#include <hip/hip_bf16.h>
#include <math.h>

#define EMBED 384
#define HEADS 6
#define HD    64
#define NF    32
#define SEQ   1025
#define SEQP  1088   // padded key stride for Vt (17*64)
#define BATCH 16
#define MTOT  (BATCH*SEQ)   // 16400
#define NCHUNK 17
#define LSTRIDE 72   // attn K LDS row stride (elems)
#define VSTR   68    // attn V LDS row stride (elems): 136B -> conflict-free b64 reads
#define TSTR   66    // qkv epilogue transpose tile stride (2-way max conflicts)

// fused prep kernel block ranges
#define NB_X2B 6150                  // (MTOT*EMBED/4)/256
#define NB_TW  144                   // 6*6*4
#define NB_RT  769                   // ceil(SEQ*HEADS*NF/256)
#define NB_VF  192                   // vt tail zero-fill: 96*64 rows x 64 cols /8 /256

typedef __bf16 bf16x8 __attribute__((ext_vector_type(8)));
typedef __bf16 bf16x4 __attribute__((ext_vector_type(4)));
typedef float  f32x4  __attribute__((ext_vector_type(4)));
typedef short  s16x4  __attribute__((ext_vector_type(4)));

#define MFMA_BF16(A,B,C) __builtin_amdgcn_mfma_f32_16x16x32_bf16((A),(B),(C),0,0,0)
// K=16 bf16 MFMA (v_mfma_f32_16x16x16_bf16 on gfx950); A/B = short4 of bf16 bits
#define MFMA16(A,B,C) __builtin_amdgcn_mfma_f32_16x16x16bf16_1k((A),(B),(C),0,0,0)

// async global->LDS, 16B per lane: per-lane global src, wave-uniform LDS dest
#define GLL16(gp, lp) __builtin_amdgcn_global_load_lds( \
    (const __attribute__((address_space(1))) void*)(gp), \
    (__attribute__((address_space(3))) void*)(lp), 16, 0, 0)

__device__ __forceinline__ __bf16 f2bf(float f){
    __hip_bfloat16 h = __float2bfloat16(f);
    return *reinterpret_cast<__bf16*>(&h);
}
__device__ __forceinline__ short bfbits(float f){
    __hip_bfloat16 h = __float2bfloat16(f);
    return *reinterpret_cast<short*>(&h);
}

// fp32 erfinv (Giles 2010)
__device__ __forceinline__ float erfinv_f(float x){
    float w = -log1pf(-x*x);
    float p;
    if (w < 5.0f){
        w -= 2.5f;
        p = 2.81022636e-08f;
        p = fmaf(p, w, 3.43273939e-07f);
        p = fmaf(p, w, -3.5233877e-06f);
        p = fmaf(p, w, -4.39150654e-06f);
        p = fmaf(p, w, 0.00021858087f);
        p = fmaf(p, w, -0.00125372503f);
        p = fmaf(p, w, -0.00417768164f);
        p = fmaf(p, w, 0.246640727f);
        p = fmaf(p, w, 1.50140941f);
    } else {
        w = sqrtf(w) - 3.0f;
        p = -0.000200214257f;
        p = fmaf(p, w, 0.000100950558f);
        p = fmaf(p, w, 0.00134934322f);
        p = fmaf(p, w, -0.00367342844f);
        p = fmaf(p, w, 0.00573950773f);
        p = fmaf(p, w, -0.0076224613f);
        p = fmaf(p, w, 0.00943887047f);
        p = fmaf(p, w, 1.00167406f);
        p = fmaf(p, w, 2.83297682f);
    }
    return p * x;
}

// -------- fused prep: x->bf16 | W transpose | rope tables | vt tail fill ----
__global__ __launch_bounds__(256) void prep_kernel(
    const float* __restrict__ x, __hip_bfloat16* __restrict__ xb,
    const float* __restrict__ Wq, const float* __restrict__ Wk,
    const float* __restrict__ Wv, const float* __restrict__ Wo,
    __hip_bfloat16* __restrict__ Wt,
    float* __restrict__ cos_t, float* __restrict__ sin_t,
    __hip_bfloat16* __restrict__ vt)
{
    __shared__ float tile[64][65];
    const int bid = blockIdx.x;
    const int tid = threadIdx.x;

    if (bid < NB_X2B){
        // ---- x fp32 -> bf16 ----
        int i = bid*256 + tid;                  // < 1,574,400 always
        float4 v = *reinterpret_cast<const float4*>(x + (size_t)i*4);
        bf16x4 b; b[0]=f2bf(v.x); b[1]=f2bf(v.y); b[2]=f2bf(v.z); b[3]=f2bf(v.w);
        *reinterpret_cast<bf16x4*>(reinterpret_cast<__bf16*>(xb) + (size_t)i*4) = b;
        return;
    }
    if (bid < NB_X2B + NB_TW){
        // ---- weight transpose: W fp32 [k][n] -> Wt bf16 [mat][n][k] ----
        int idx = bid - NB_X2B;                 // 0..143
        const int mat = idx / 36;
        const int rem = idx % 36;
        const int kx = rem / 6, ny = rem % 6;
        const float* W = (mat==0)?Wq:(mat==1)?Wk:(mat==2)?Wv:Wo;
        const int k0 = kx*64, n0 = ny*64;
        const int c = tid & 63, rq = tid >> 6;
        #pragma unroll
        for (int i = 0; i < 16; ++i){
            int row = rq*16 + i;
            tile[row][c] = W[(size_t)(k0+row)*EMBED + n0 + c];
        }
        __syncthreads();
        #pragma unroll
        for (int i = 0; i < 16; ++i){
            int nr = rq*16 + i;
            Wt[((size_t)mat*EMBED + n0 + nr)*EMBED + k0 + c] = __float2bfloat16(tile[c][nr]);
        }
        return;
    }
    if (bid < NB_X2B + NB_TW + NB_RT){
        // ---- rope tables ----
        int idx = (bid - NB_X2B - NB_TW)*256 + tid;
        if (idx >= SEQ*HEADS*NF) return;
        int f  = idx & (NF-1);
        int hf = idx / NF;
        int h  = hf % HEADS;
        int s  = hf / HEADS;

        double xd = 2.0;
        #pragma unroll
        for (int it = 0; it < 10; ++it) xd = cbrt(1.0 + xd);
        float a1 = (float)(1.0 / xd);
        float a2 = a1 * a1;

        float fi = (float)(h*NF + f + 1);
        float z1 = fmodf(fi * a1, 1.0f);
        float z2 = fmodf(fi * a2, 1.0f);
        float d1 = erfinv_f(2.0f*z1 - 1.0f);
        float d2 = erfinv_f(2.0f*z2 - 1.0f);
        float inv = 1.0f / sqrtf(d1*d1 + d2*d2);
        d1 *= inv; d2 *= inv;

        float omega = 0.1f * powf(10000.0f, (float)f / 31.0f);
        float fx = d1 * omega, fy = d2 * omega;

        float cx = 0.0f, cy = 0.0f;
        if (s > 0){
            int pi = s - 1;
            cx = (float)(pi & 31) / 31.0f * 2.0f - 1.0f;
            cy = (float)(pi >> 5) / 31.0f * 2.0f - 1.0f;
        }
        float theta = fx*cx + fy*cy;
        float sv, cv;
        sincosf(theta, &sv, &cv);
        cos_t[idx] = cv;
        sin_t[idx] = sv;
        return;
    }
    // ---- vt tail zero-fill: cols 1024..1087 of all 96*64 rows ----
    {
        int g = (bid - NB_X2B - NB_TW - NB_RT)*256 + tid;   // < 49152 exact
        int row = g >> 3, sg = g & 7;
        bf16x8 z = {};
        *reinterpret_cast<bf16x8*>(reinterpret_cast<__bf16*>(vt)
            + (size_t)row*SEQP + 1024 + sg*8) = z;
    }
}

// QKV: one big GEMM xb[16400x384] @ Wt[1152x384]^T, 128x128 tiles.
// grid (129, 9), block 256 (4 waves, 2x2). Wave = 64 rows x one head's 64 cols.
// m97-style pipeline: double-buffered LDS via global_load_lds width=16.
// Epilogue: RoPE for q/k; V^T written DIRECTLY (LDS transpose through the
// dead tile buffers) -- vt_transpose kernel and vbuf eliminated.
__global__ __launch_bounds__(256, 3) void qkv_rope_kernel(
    const __hip_bfloat16* __restrict__ xb_,
    const __hip_bfloat16* __restrict__ Wt,
    const float* __restrict__ cos_t,
    const float* __restrict__ sin_t,
    __hip_bfloat16* __restrict__ qbuf,
    __hip_bfloat16* __restrict__ kbuf,
    __hip_bfloat16* __restrict__ vtbuf)
{
    __shared__ __align__(16) __bf16 smem[16384];   // 32KB: xs dbuf + bt dbuf
    const int tid = threadIdx.x;
    const int m0 = blockIdx.x * 128;
    const int j  = blockIdx.y;
    const __bf16* xb = reinterpret_cast<const __bf16*>(xb_);
    const __bf16* wt = reinterpret_cast<const __bf16*>(Wt);
    __bf16* vtb = reinterpret_cast<__bf16*>(vtbuf);

    const int w = tid >> 6;
    const int lane = tid & 63;
    const int quad = lane >> 4, low = lane & 15;
    const int rg = lane >> 2, cg = lane & 3;   // 16 rows x 4 granules per chunk

    // wave w stages chunks w*2, w*2+1 (16 rows each) of both A and B
    int arow[2], brow[2], loff[2];
    #pragma unroll
    for (int i = 0; i < 2; ++i){
        int row = (w*2 + i)*16 + rg;
        int am = m0 + row; if (am > MTOT-1) am = MTOT-1;
        arow[i] = am;
        brow[i] = j*128 + row;          // < 1152 always
        loff[i] = (w*2 + i)*1024;       // bytes: 16 rows x 64B
    }

    // prologue: stage tile 0 into buffer 0 (xs at smem[0], bt at smem[8192])
    #pragma unroll
    for (int i = 0; i < 2; ++i){
        GLL16(xb + (size_t)arow[i]*EMBED + cg*8, (char*)smem + loff[i]);
        GLL16(wt + (size_t)brow[i]*EMBED + cg*8, (char*)(smem + 8192) + loff[i]);
    }
    __syncthreads();

    const int mh = w >> 1, nh = w & 1;
    const int mw0 = m0 + mh*64;

    f32x4 acc[4][4] = {};
    for (int kb = 0; kb < 12; ++kb){
        const int cur = kb & 1;
        const __bf16* xcur = smem + cur*4096;
        const __bf16* bcur = smem + 8192 + cur*4096;
        // issue tile k+1's loads into the alternate buffer (fly over compute)
        if (kb < 11){
            const int k1 = (kb+1)*32;
            __bf16* xnxt = smem + (cur^1)*4096;
            __bf16* bnxt = smem + 8192 + (cur^1)*4096;
            #pragma unroll
            for (int i = 0; i < 2; ++i){
                GLL16(xb + (size_t)arow[i]*EMBED + k1 + cg*8, (char*)xnxt + loff[i]);
                GLL16(wt + (size_t)brow[i]*EMBED + k1 + cg*8, (char*)bnxt + loff[i]);
            }
        }
        bf16x8 af[4], bfr[4];
        #pragma unroll
        for (int mt = 0; mt < 4; ++mt)
            af[mt] = *reinterpret_cast<const bf16x8*>(&xcur[(mh*64 + mt*16 + low)*32 + quad*8]);
        #pragma unroll
        for (int t = 0; t < 4; ++t)
            bfr[t] = *reinterpret_cast<const bf16x8*>(&bcur[(nh*64 + t*16 + low)*32 + quad*8]);
        #pragma unroll
        for (int t = 0; t < 4; ++t)
            #pragma unroll
            for (int mt = 0; mt < 4; ++mt)
                acc[mt][t] = MFMA_BF16(af[mt], bfr[t], acc[mt][t]);
        if (kb < 11) __syncthreads();   // drains vmcnt(0): tile k+1 landed
    }

    const int n64 = j*2 + nh;           // 0..17
    const int mat = n64 / 6;            // j-uniform (2j and 2j+1 share mat)
    const int h   = n64 % 6;

    if (mat == 2){
        // ---- V^T direct store via LDS transpose (block-uniform branch) ----
        __syncthreads();                // main-loop LDS reads done
        const int d8 = lane >> 3, sg = lane & 7;
        const int m0c = mw0 + sg*8;
        const int b0 = m0c / SEQ;
        const int s0 = m0c - b0*SEQ;
        const bool fast = (m0c + 7 < MTOT) && (s0 + 7 < SEQ);
        #pragma unroll
        for (int ph = 0; ph < 2; ++ph){
            if (mh == ph){
                __bf16* tl = smem + nh*4608;       // 64 x TSTR(66)
                #pragma unroll
                for (int mt = 0; mt < 4; ++mt)
                    #pragma unroll
                    for (int t = 0; t < 4; ++t)
                        #pragma unroll
                        for (int r = 0; r < 4; ++r)
                            tl[(mt*16 + quad*4 + r)*TSTR + t*16 + low] = f2bf(acc[mt][t][r]);
            }
            __syncthreads();
            if (mh == ph){
                __bf16* tl = smem + nh*4608;
                #pragma unroll
                for (int db = 0; db < 8; ++db){
                    const int d = db*8 + d8;
                    if (fast){
                        bf16x8 val;
                        #pragma unroll
                        for (int e = 0; e < 8; ++e) val[e] = tl[(sg*8+e)*TSTR + d];
                        *reinterpret_cast<bf16x8*>(
                            vtb + ((size_t)(b0*HEADS + h)*HD + d)*SEQP + s0) = val;
                    } else {
                        #pragma unroll
                        for (int e = 0; e < 8; ++e){
                            int m = m0c + e;
                            if (m < MTOT){
                                int bb = m / SEQ, ss = m - bb*SEQ;
                                vtb[((size_t)(bb*HEADS + h)*HD + d)*SEQP + ss] =
                                    tl[(sg*8+e)*TSTR + d];
                            }
                        }
                    }
                }
            }
            __syncthreads();
        }
    } else {
        __hip_bfloat16* ob = (mat == 0) ? qbuf : kbuf;
        const float qs_ = (mat == 0) ? 0.125f : 1.0f;
        #pragma unroll
        for (int mt = 0; mt < 4; ++mt)
            #pragma unroll
            for (int t = 0; t < 2; ++t)
                #pragma unroll
                for (int r = 0; r < 4; ++r){
                    int m = mw0 + mt*16 + quad*4 + r;
                    if (m < MTOT){
                        int b = m / SEQ, s = m % SEQ;
                        int f = t*16 + low;
                        float cv = cos_t[(s*HEADS + h)*NF + f];
                        float sv = sin_t[(s*HEADS + h)*NF + f];
                        float x1 = acc[mt][t][r];
                        float y1 = acc[mt][t+2][r];
                        size_t base = ((size_t)(b*HEADS + h)*SEQ + s)*HD;
                        ob[base + f]      = __float2bfloat16((x1*cv - y1*sv)*qs_);
                        ob[base + NF + f] = __float2bfloat16((x1*sv + y1*cv)*qs_);
                    }
                }
    }
}

// Flash attention, fixed-base softmax (no running max: scores bounded ~|5|).
// S^T = K.Q^T (qrow in-lane). PV = P.V via 16x16x16 MFMA with P entirely
// in registers. [round-12 exact, measured 54.4us]
__global__ __launch_bounds__(256, 4) void attn_kernel(
    const __hip_bfloat16* __restrict__ qbuf,
    const __hip_bfloat16* __restrict__ kbuf,
    const __hip_bfloat16* __restrict__ vtbuf,
    __hip_bfloat16* __restrict__ aout)
{
    __shared__ __align__(16) __bf16 kls[64*LSTRIDE];    // [key][feat]
    __shared__ __align__(16) __bf16 vls[64*VSTR];       // [d][key], 136B stride
    const int tid  = threadIdx.x;
    const int w    = tid >> 6;
    const int lane = tid & 63;
    const int quad = lane >> 4, low = lane & 15;
    const int id = blockIdx.x;
    const int bh = id % 96;
    const int qt = id / 96;
    const int b = bh / HEADS, h = bh % HEADS;
    const __bf16* qb = reinterpret_cast<const __bf16*>(qbuf);
    const __bf16* kb = reinterpret_cast<const __bf16*>(kbuf);
    const __bf16* vt = reinterpret_cast<const __bf16*>(vtbuf);
    const size_t base   = (size_t)bh * SEQ * HD;
    const size_t vtbase = (size_t)bh * HD * SEQP;
    const int q0 = qt*128 + w*32;

    int srow[2], sgk[2], soffk[2], soffv[2];
    #pragma unroll
    for (int i = 0; i < 2; ++i){
        int ch = tid + i*256;
        srow[i] = ch >> 3; sgk[i] = ch & 7;
        soffk[i] = srow[i]*LSTRIDE + sgk[i]*8;
        soffv[i] = srow[i]*VSTR    + sgk[i]*8;
    }

    bf16x8 bq[2][2];
    #pragma unroll
    for (int nt = 0; nt < 2; ++nt){
        int qs = q0 + nt*16 + low; if (qs > SEQ-1) qs = SEQ-1;
        #pragma unroll
        for (int ks = 0; ks < 2; ++ks)
            bq[nt][ks] = *reinterpret_cast<const bf16x8*>(qb + base + (size_t)qs*HD + ks*32 + quad*8);
    }

    bf16x8 kr[2], vr[2];
    #pragma unroll
    for (int i = 0; i < 2; ++i){
        int kk = srow[i]; if (kk > SEQ-1) kk = SEQ-1;
        kr[i] = *reinterpret_cast<const bf16x8*>(kb + base + (size_t)kk*HD + sgk[i]*8);
        vr[i] = *reinterpret_cast<const bf16x8*>(vt + vtbase + (size_t)srow[i]*SEQP + sgk[i]*8);
    }

    f32x4 o[2][4] = {};          // o[nt][dt]: row=q (quad*4+r), col=d (dt*16+low)
    float l_i[2] = {0.f, 0.f};

    for (int c = 0; c < NCHUNK; ++c){
        const int c0 = c*64;
        __syncthreads();
        #pragma unroll
        for (int i = 0; i < 2; ++i){
            *reinterpret_cast<bf16x8*>(&kls[soffk[i]]) = kr[i];
            bf16x4 vlo = __builtin_shufflevector(vr[i], vr[i], 0,1,2,3);
            bf16x4 vhi = __builtin_shufflevector(vr[i], vr[i], 4,5,6,7);
            *reinterpret_cast<bf16x4*>(&vls[soffv[i]])     = vlo;
            *reinterpret_cast<bf16x4*>(&vls[soffv[i] + 4]) = vhi;
        }
        __syncthreads();
        if (c + 1 < NCHUNK){
            const int c1 = c0 + 64;
            #pragma unroll
            for (int i = 0; i < 2; ++i){
                int kk = c1 + srow[i]; if (kk > SEQ-1) kk = SEQ-1;
                kr[i] = *reinterpret_cast<const bf16x8*>(kb + base + (size_t)kk*HD + sgk[i]*8);
                vr[i] = *reinterpret_cast<const bf16x8*>(vt + vtbase + (size_t)srow[i]*SEQP + c1 + sgk[i]*8);
            }
        }
        f32x4 st[4][2] = {};
        #pragma unroll
        for (int kt = 0; kt < 4; ++kt)
            #pragma unroll
            for (int ks = 0; ks < 2; ++ks){
                bf16x8 ak = *reinterpret_cast<const bf16x8*>(&kls[(kt*16 + low)*LSTRIDE + ks*32 + quad*8]);
                #pragma unroll
                for (int nt = 0; nt < 2; ++nt)
                    st[kt][nt] = MFMA_BF16(ak, bq[nt][ks], st[kt][nt]);
            }
        if (c0 + 64 > SEQ){
            #pragma unroll
            for (int kt = 0; kt < 4; ++kt)
                #pragma unroll
                for (int r = 0; r < 4; ++r){
                    int key = c0 + kt*16 + quad*4 + r;
                    if (key >= SEQ){ st[kt][0][r] = -1e30f; st[kt][1][r] = -1e30f; }
                }
        }
        // exp + in-lane l partial + pack P to bf16 A-fragments (in-register)
        s16x4 pa[4][2];
        #pragma unroll
        for (int nt = 0; nt < 2; ++nt)
            #pragma unroll
            for (int kt = 0; kt < 4; ++kt)
                #pragma unroll
                for (int r = 0; r < 4; ++r){
                    float p = __expf(st[kt][nt][r]);
                    l_i[nt] += p;
                    pa[kt][nt][r] = bfbits(p);
                }
        // O += P.V, A=P in-register, B=V from vls (conflict-free b64 reads)
        #pragma unroll
        for (int kt = 0; kt < 4; ++kt)
            #pragma unroll
            for (int dt = 0; dt < 4; ++dt){
                const s16x4 bv = *reinterpret_cast<const s16x4*>(&vls[(dt*16 + low)*VSTR + kt*16 + quad*4]);
                #pragma unroll
                for (int nt = 0; nt < 2; ++nt)
                    o[nt][dt] = MFMA16(pa[kt][nt], bv, o[nt][dt]);
            }
    }

    // reduce l across quads (lanes sharing 'low'), redistribute to output rows
    #pragma unroll
    for (int nt = 0; nt < 2; ++nt){
        l_i[nt] += __shfl_xor(l_i[nt], 16, 64);
        l_i[nt] += __shfl_xor(l_i[nt], 32, 64);
    }
    float lq[2][4];
    #pragma unroll
    for (int nt = 0; nt < 2; ++nt)
        #pragma unroll
        for (int r = 0; r < 4; ++r)
            lq[nt][r] = __shfl(l_i[nt], quad*4 + r, 64);

    #pragma unroll
    for (int nt = 0; nt < 2; ++nt)
        #pragma unroll
        for (int r = 0; r < 4; ++r){
            int s = q0 + nt*16 + quad*4 + r;
            if (s < SEQ){
                float inv = 1.0f / lq[nt][r];
                __hip_bfloat16* dst = aout + ((size_t)b*SEQ + s)*EMBED + h*HD;
                #pragma unroll
                for (int dt = 0; dt < 4; ++dt)
                    dst[dt*16 + low] = __float2bfloat16(o[nt][dt][r]*inv);
            }
        }
}

// out = attn @ Wo + bo. NEW: 64x64 tiles, 128 threads (2 waves x 32x64),
// grid (257, 6) = 1542 blocks ~= 6/CU -> 12 waves/CU (was 6 waves/CU:
// latency-bound, ~50+us hidden under the attn top-5 cutoff all session).
__global__ __launch_bounds__(128) void outproj_kernel(
    const __hip_bfloat16* __restrict__ a,
    const __hip_bfloat16* __restrict__ Wt,
    const float* __restrict__ bo,
    float* __restrict__ out)
{
    __shared__ __align__(16) __bf16 xs[2][64*32];
    __shared__ __align__(16) __bf16 bt2[2][64*32];
    const int tid = threadIdx.x;          // 0..127
    const int m0 = blockIdx.x * 64;
    const int n0 = blockIdx.y * 64;
    const __bf16* ab = reinterpret_cast<const __bf16*>(a);
    const __bf16* wt = reinterpret_cast<const __bf16*>(Wt) + (size_t)3*EMBED*EMBED;

    const int w = tid >> 6;               // 0..1
    const int lane = tid & 63;
    const int quad = lane >> 4, low = lane & 15;
    const int rg = lane >> 2, cg = lane & 3;

    // A and B: 4 chunks of 16 rows each; wave w stages chunks w*2, w*2+1
    int arow[2], brow[2], coff[2];
    #pragma unroll
    for (int i = 0; i < 2; ++i){
        int row = (w*2 + i)*16 + rg;
        int am = m0 + row; if (am > MTOT-1) am = MTOT-1;
        arow[i] = am;
        brow[i] = n0 + row;               // Wo^T row (n), < 384
        coff[i] = (w*2 + i)*1024;         // bytes
    }

    // prologue: stage tile 0 into buffer 0
    #pragma unroll
    for (int i = 0; i < 2; ++i){
        GLL16(ab + (size_t)arow[i]*EMBED + cg*8, (char*)xs[0] + coff[i]);
        GLL16(wt + (size_t)brow[i]*EMBED + cg*8, (char*)bt2[0] + coff[i]);
    }
    __syncthreads();

    f32x4 acc[2][4] = {};
    for (int kb = 0; kb < 12; ++kb){
        const int cur = kb & 1;
        if (kb < 11){
            const int k1 = (kb+1)*32;
            #pragma unroll
            for (int i = 0; i < 2; ++i){
                GLL16(ab + (size_t)arow[i]*EMBED + k1 + cg*8, (char*)xs[cur^1] + coff[i]);
                GLL16(wt + (size_t)brow[i]*EMBED + k1 + cg*8, (char*)bt2[cur^1] + coff[i]);
            }
        }
        bf16x8 af[2], bfr[4];
        #pragma unroll
        for (int mt = 0; mt < 2; ++mt)
            af[mt] = *reinterpret_cast<const bf16x8*>(&xs[cur][(w*32 + mt*16 + low)*32 + quad*8]);
        #pragma unroll
        for (int t = 0; t < 4; ++t)
            bfr[t] = *reinterpret_cast<const bf16x8*>(&bt2[cur][(t*16 + low)*32 + quad*8]);
        #pragma unroll
        for (int t = 0; t < 4; ++t)
            #pragma unroll
            for (int mt = 0; mt < 2; ++mt)
                acc[mt][t] = MFMA_BF16(af[mt], bfr[t], acc[mt][t]);
        if (kb < 11) __syncthreads();
    }

    #pragma unroll
    for (int t = 0; t < 4; ++t){
        const int n = n0 + t*16 + low;
        const float bias = bo[n];
        #pragma unroll
        for (int mt = 0; mt < 2; ++mt)
            #pragma unroll
            for (int r = 0; r < 4; ++r){
                const int m = m0 + w*32 + mt*16 + quad*4 + r;
                if (m < MTOT) out[(size_t)m*EMBED + n] = acc[mt][t][r] + bias;
            }
    }
}

extern "C" void kernel_launch(void* const* d_in, const int* in_sizes, int n_in,
                              void* d_out, int out_size, void* d_ws, size_t ws_size,
                              hipStream_t stream)
{
    const float* x  = (const float*)d_in[0];
    const float* Wq = (const float*)d_in[1];
    const float* Wk = (const float*)d_in[2];
    const float* Wv = (const float*)d_in[3];
    const float* Wo = (const float*)d_in[4];
    const float* bo = (const float*)d_in[5];
    float* out = (float*)d_out;

    const size_t NE = (size_t)MTOT * EMBED;                 // 6,297,600
    const size_t VT = (size_t)BATCH*HEADS*HD*SEQP;          // padded V^T elems
    char* ws = (char*)d_ws;
    size_t off = 0;
    __hip_bfloat16* qbuf = (__hip_bfloat16*)(ws + off); off += 2*NE;
    __hip_bfloat16* kbuf = (__hip_bfloat16*)(ws + off); off += 2*NE;
    __hip_bfloat16* abuf = (__hip_bfloat16*)(ws + off); off += 2*NE;
    __hip_bfloat16* xbuf = (__hip_bfloat16*)(ws + off); off += 2*NE;
    __hip_bfloat16* vt   = (__hip_bfloat16*)(ws + off); off += 2*VT;
    __hip_bfloat16* Wt   = (__hip_bfloat16*)(ws + off); off += (size_t)4*EMBED*EMBED*2;
    float* cos_t = (float*)(ws + off); off += (size_t)SEQ*HEADS*NF*4;
    float* sin_t = (float*)(ws + off); off += (size_t)SEQ*HEADS*NF*4;

    prep_kernel<<<dim3(NB_X2B + NB_TW + NB_RT + NB_VF), dim3(256), 0, stream>>>(
        x, xbuf, Wq, Wk, Wv, Wo, Wt, cos_t, sin_t, vt);
    qkv_rope_kernel<<<dim3((MTOT + 127)/128, 9), dim3(256), 0, stream>>>(xbuf, Wt, cos_t, sin_t, qbuf, kbuf, vt);
    attn_kernel<<<dim3(864), dim3(256), 0, stream>>>(qbuf, kbuf, vt, abuf);
    outproj_kernel<<<dim3((MTOT + 63)/64, 6), dim3(128), 0, stream>>>(abuf, Wt, bo, out);
}

// Round 19
// 199.031 us; speedup vs baseline: 1.0293x; 1.0167x over previous
//
#include <hip/hip_runtime.h>
#include <hip/hip_bf16.h>
#include <math.h>

#define EMBED 384
#define HEADS 6
#define HD    64
#define NF    32
#define SEQ   1025
#define SEQP  1088   // padded key stride for Vt (17*64)
#define BATCH 16
#define MTOT  (BATCH*SEQ)   // 16400
#define NCHUNK 17
#define LSTRIDE 72   // attn K LDS row stride (elems)
#define VSTR   68    // attn V LDS row stride (elems): 136B -> conflict-free b64 reads
#define TSTR   66    // qkv epilogue transpose tile stride (2-way max conflicts)

// fused prep kernel block ranges
#define NB_X2B 6150                  // (MTOT*EMBED/4)/256
#define NB_TW  144                   // 6*6*4
#define NB_RT  769                   // ceil(SEQ*HEADS*NF/256)
#define NB_VF  192                   // vt tail zero-fill: 96*64 rows x 64 cols /8 /256

typedef __bf16 bf16x8 __attribute__((ext_vector_type(8)));
typedef __bf16 bf16x4 __attribute__((ext_vector_type(4)));
typedef float  f32x4  __attribute__((ext_vector_type(4)));
typedef short  s16x4  __attribute__((ext_vector_type(4)));

#define MFMA_BF16(A,B,C) __builtin_amdgcn_mfma_f32_16x16x32_bf16((A),(B),(C),0,0,0)
// K=16 bf16 MFMA (v_mfma_f32_16x16x16_bf16 on gfx950); A/B = short4 of bf16 bits
#define MFMA16(A,B,C) __builtin_amdgcn_mfma_f32_16x16x16bf16_1k((A),(B),(C),0,0,0)

// async global->LDS, 16B per lane: per-lane global src, wave-uniform LDS dest
#define GLL16(gp, lp) __builtin_amdgcn_global_load_lds( \
    (const __attribute__((address_space(1))) void*)(gp), \
    (__attribute__((address_space(3))) void*)(lp), 16, 0, 0)

__device__ __forceinline__ __bf16 f2bf(float f){
    __hip_bfloat16 h = __float2bfloat16(f);
    return *reinterpret_cast<__bf16*>(&h);
}
__device__ __forceinline__ short bfbits(float f){
    __hip_bfloat16 h = __float2bfloat16(f);
    return *reinterpret_cast<short*>(&h);
}

// fp32 erfinv (Giles 2010)
__device__ __forceinline__ float erfinv_f(float x){
    float w = -log1pf(-x*x);
    float p;
    if (w < 5.0f){
        w -= 2.5f;
        p = 2.81022636e-08f;
        p = fmaf(p, w, 3.43273939e-07f);
        p = fmaf(p, w, -3.5233877e-06f);
        p = fmaf(p, w, -4.39150654e-06f);
        p = fmaf(p, w, 0.00021858087f);
        p = fmaf(p, w, -0.00125372503f);
        p = fmaf(p, w, -0.00417768164f);
        p = fmaf(p, w, 0.246640727f);
        p = fmaf(p, w, 1.50140941f);
    } else {
        w = sqrtf(w) - 3.0f;
        p = -0.000200214257f;
        p = fmaf(p, w, 0.000100950558f);
        p = fmaf(p, w, 0.00134934322f);
        p = fmaf(p, w, -0.00367342844f);
        p = fmaf(p, w, 0.00573950773f);
        p = fmaf(p, w, -0.0076224613f);
        p = fmaf(p, w, 0.00943887047f);
        p = fmaf(p, w, 1.00167406f);
        p = fmaf(p, w, 2.83297682f);
    }
    return p * x;
}

// -------- fused prep: x->bf16 | W transpose | rope tables | vt tail fill ----
// a1/a2 (golden-ratio direction base) computed on HOST: thread-invariant,
// previously a 10-iteration double cbrt loop per rope thread (~4k cycles).
__global__ __launch_bounds__(256) void prep_kernel(
    const float* __restrict__ x, __hip_bfloat16* __restrict__ xb,
    const float* __restrict__ Wq, const float* __restrict__ Wk,
    const float* __restrict__ Wv, const float* __restrict__ Wo,
    __hip_bfloat16* __restrict__ Wt,
    float* __restrict__ cos_t, float* __restrict__ sin_t,
    __hip_bfloat16* __restrict__ vt,
    float a1, float a2)
{
    __shared__ float tile[64][65];
    const int bid = blockIdx.x;
    const int tid = threadIdx.x;

    if (bid < NB_X2B){
        // ---- x fp32 -> bf16 ----
        int i = bid*256 + tid;                  // < 1,574,400 always
        float4 v = *reinterpret_cast<const float4*>(x + (size_t)i*4);
        bf16x4 b; b[0]=f2bf(v.x); b[1]=f2bf(v.y); b[2]=f2bf(v.z); b[3]=f2bf(v.w);
        *reinterpret_cast<bf16x4*>(reinterpret_cast<__bf16*>(xb) + (size_t)i*4) = b;
        return;
    }
    if (bid < NB_X2B + NB_TW){
        // ---- weight transpose: W fp32 [k][n] -> Wt bf16 [mat][n][k] ----
        int idx = bid - NB_X2B;                 // 0..143
        const int mat = idx / 36;
        const int rem = idx % 36;
        const int kx = rem / 6, ny = rem % 6;
        const float* W = (mat==0)?Wq:(mat==1)?Wk:(mat==2)?Wv:Wo;
        const int k0 = kx*64, n0 = ny*64;
        const int c = tid & 63, rq = tid >> 6;
        #pragma unroll
        for (int i = 0; i < 16; ++i){
            int row = rq*16 + i;
            tile[row][c] = W[(size_t)(k0+row)*EMBED + n0 + c];
        }
        __syncthreads();
        #pragma unroll
        for (int i = 0; i < 16; ++i){
            int nr = rq*16 + i;
            Wt[((size_t)mat*EMBED + n0 + nr)*EMBED + k0 + c] = __float2bfloat16(tile[c][nr]);
        }
        return;
    }
    if (bid < NB_X2B + NB_TW + NB_RT){
        // ---- rope tables (constants hoisted to host) ----
        int idx = (bid - NB_X2B - NB_TW)*256 + tid;
        if (idx >= SEQ*HEADS*NF) return;
        int f  = idx & (NF-1);
        int hf = idx / NF;
        int h  = hf % HEADS;
        int s  = hf / HEADS;

        float fi = (float)(h*NF + f + 1);
        float z1 = fmodf(fi * a1, 1.0f);
        float z2 = fmodf(fi * a2, 1.0f);
        float d1 = erfinv_f(2.0f*z1 - 1.0f);
        float d2 = erfinv_f(2.0f*z2 - 1.0f);
        float inv = 1.0f / sqrtf(d1*d1 + d2*d2);
        d1 *= inv; d2 *= inv;

        float omega = 0.1f * powf(10000.0f, (float)f / 31.0f);
        float fx = d1 * omega, fy = d2 * omega;

        float cx = 0.0f, cy = 0.0f;
        if (s > 0){
            int pi = s - 1;
            cx = (float)(pi & 31) / 31.0f * 2.0f - 1.0f;
            cy = (float)(pi >> 5) / 31.0f * 2.0f - 1.0f;
        }
        float theta = fx*cx + fy*cy;
        float sv, cv;
        sincosf(theta, &sv, &cv);
        cos_t[idx] = cv;
        sin_t[idx] = sv;
        return;
    }
    // ---- vt tail zero-fill: cols 1024..1087 of all 96*64 rows ----
    {
        int g = (bid - NB_X2B - NB_TW - NB_RT)*256 + tid;   // < 49152 exact
        int row = g >> 3, sg = g & 7;
        bf16x8 z = {};
        *reinterpret_cast<bf16x8*>(reinterpret_cast<__bf16*>(vt)
            + (size_t)row*SEQP + 1024 + sg*8) = z;
    }
}

// QKV: one big GEMM xb[16400x384] @ Wt[1152x384]^T, 128x128 tiles.
// grid (129, 9), block 256 (4 waves, 2x2). Wave = 64 rows x one head's 64 cols.
// m97-style pipeline: double-buffered LDS via global_load_lds width=16.
// Epilogue: RoPE for q/k; V^T written DIRECTLY (LDS transpose through the
// dead tile buffers) -- vt_transpose kernel and vbuf eliminated.
__global__ __launch_bounds__(256, 3) void qkv_rope_kernel(
    const __hip_bfloat16* __restrict__ xb_,
    const __hip_bfloat16* __restrict__ Wt,
    const float* __restrict__ cos_t,
    const float* __restrict__ sin_t,
    __hip_bfloat16* __restrict__ qbuf,
    __hip_bfloat16* __restrict__ kbuf,
    __hip_bfloat16* __restrict__ vtbuf)
{
    __shared__ __align__(16) __bf16 smem[16384];   // 32KB: xs dbuf + bt dbuf
    const int tid = threadIdx.x;
    const int m0 = blockIdx.x * 128;
    const int j  = blockIdx.y;
    const __bf16* xb = reinterpret_cast<const __bf16*>(xb_);
    const __bf16* wt = reinterpret_cast<const __bf16*>(Wt);
    __bf16* vtb = reinterpret_cast<__bf16*>(vtbuf);

    const int w = tid >> 6;
    const int lane = tid & 63;
    const int quad = lane >> 4, low = lane & 15;
    const int rg = lane >> 2, cg = lane & 3;   // 16 rows x 4 granules per chunk

    // wave w stages chunks w*2, w*2+1 (16 rows each) of both A and B
    int arow[2], brow[2], loff[2];
    #pragma unroll
    for (int i = 0; i < 2; ++i){
        int row = (w*2 + i)*16 + rg;
        int am = m0 + row; if (am > MTOT-1) am = MTOT-1;
        arow[i] = am;
        brow[i] = j*128 + row;          // < 1152 always
        loff[i] = (w*2 + i)*1024;       // bytes: 16 rows x 64B
    }

    // prologue: stage tile 0 into buffer 0 (xs at smem[0], bt at smem[8192])
    #pragma unroll
    for (int i = 0; i < 2; ++i){
        GLL16(xb + (size_t)arow[i]*EMBED + cg*8, (char*)smem + loff[i]);
        GLL16(wt + (size_t)brow[i]*EMBED + cg*8, (char*)(smem + 8192) + loff[i]);
    }
    __syncthreads();

    const int mh = w >> 1, nh = w & 1;
    const int mw0 = m0 + mh*64;

    f32x4 acc[4][4] = {};
    for (int kb = 0; kb < 12; ++kb){
        const int cur = kb & 1;
        const __bf16* xcur = smem + cur*4096;
        const __bf16* bcur = smem + 8192 + cur*4096;
        // issue tile k+1's loads into the alternate buffer (fly over compute)
        if (kb < 11){
            const int k1 = (kb+1)*32;
            __bf16* xnxt = smem + (cur^1)*4096;
            __bf16* bnxt = smem + 8192 + (cur^1)*4096;
            #pragma unroll
            for (int i = 0; i < 2; ++i){
                GLL16(xb + (size_t)arow[i]*EMBED + k1 + cg*8, (char*)xnxt + loff[i]);
                GLL16(wt + (size_t)brow[i]*EMBED + k1 + cg*8, (char*)bnxt + loff[i]);
            }
        }
        bf16x8 af[4], bfr[4];
        #pragma unroll
        for (int mt = 0; mt < 4; ++mt)
            af[mt] = *reinterpret_cast<const bf16x8*>(&xcur[(mh*64 + mt*16 + low)*32 + quad*8]);
        #pragma unroll
        for (int t = 0; t < 4; ++t)
            bfr[t] = *reinterpret_cast<const bf16x8*>(&bcur[(nh*64 + t*16 + low)*32 + quad*8]);
        #pragma unroll
        for (int t = 0; t < 4; ++t)
            #pragma unroll
            for (int mt = 0; mt < 4; ++mt)
                acc[mt][t] = MFMA_BF16(af[mt], bfr[t], acc[mt][t]);
        if (kb < 11) __syncthreads();   // drains vmcnt(0): tile k+1 landed
    }

    const int n64 = j*2 + nh;           // 0..17
    const int mat = n64 / 6;            // j-uniform (2j and 2j+1 share mat)
    const int h   = n64 % 6;

    if (mat == 2){
        // ---- V^T direct store via LDS transpose (block-uniform branch) ----
        __syncthreads();                // main-loop LDS reads done
        const int d8 = lane >> 3, sg = lane & 7;
        const int m0c = mw0 + sg*8;
        const int b0 = m0c / SEQ;
        const int s0 = m0c - b0*SEQ;
        const bool fast = (m0c + 7 < MTOT) && (s0 + 7 < SEQ);
        #pragma unroll
        for (int ph = 0; ph < 2; ++ph){
            if (mh == ph){
                __bf16* tl = smem + nh*4608;       // 64 x TSTR(66)
                #pragma unroll
                for (int mt = 0; mt < 4; ++mt)
                    #pragma unroll
                    for (int t = 0; t < 4; ++t)
                        #pragma unroll
                        for (int r = 0; r < 4; ++r)
                            tl[(mt*16 + quad*4 + r)*TSTR + t*16 + low] = f2bf(acc[mt][t][r]);
            }
            __syncthreads();
            if (mh == ph){
                __bf16* tl = smem + nh*4608;
                #pragma unroll
                for (int db = 0; db < 8; ++db){
                    const int d = db*8 + d8;
                    if (fast){
                        bf16x8 val;
                        #pragma unroll
                        for (int e = 0; e < 8; ++e) val[e] = tl[(sg*8+e)*TSTR + d];
                        *reinterpret_cast<bf16x8*>(
                            vtb + ((size_t)(b0*HEADS + h)*HD + d)*SEQP + s0) = val;
                    } else {
                        #pragma unroll
                        for (int e = 0; e < 8; ++e){
                            int m = m0c + e;
                            if (m < MTOT){
                                int bb = m / SEQ, ss = m - bb*SEQ;
                                vtb[((size_t)(bb*HEADS + h)*HD + d)*SEQP + ss] =
                                    tl[(sg*8+e)*TSTR + d];
                            }
                        }
                    }
                }
            }
            __syncthreads();
        }
    } else {
        __hip_bfloat16* ob = (mat == 0) ? qbuf : kbuf;
        const float qs_ = (mat == 0) ? 0.125f : 1.0f;
        #pragma unroll
        for (int mt = 0; mt < 4; ++mt)
            #pragma unroll
            for (int t = 0; t < 2; ++t)
                #pragma unroll
                for (int r = 0; r < 4; ++r){
                    int m = mw0 + mt*16 + quad*4 + r;
                    if (m < MTOT){
                        int b = m / SEQ, s = m % SEQ;
                        int f = t*16 + low;
                        float cv = cos_t[(s*HEADS + h)*NF + f];
                        float sv = sin_t[(s*HEADS + h)*NF + f];
                        float x1 = acc[mt][t][r];
                        float y1 = acc[mt][t+2][r];
                        size_t base = ((size_t)(b*HEADS + h)*SEQ + s)*HD;
                        ob[base + f]      = __float2bfloat16((x1*cv - y1*sv)*qs_);
                        ob[base + NF + f] = __float2bfloat16((x1*sv + y1*cv)*qs_);
                    }
                }
    }
}

// Flash attention, fixed-base softmax (no running max: scores bounded ~|5|).
// S^T = K.Q^T (qrow in-lane). PV = P.V via 16x16x16 MFMA with P entirely
// in registers. [round-12 exact, measured 54.4us]
__global__ __launch_bounds__(256, 4) void attn_kernel(
    const __hip_bfloat16* __restrict__ qbuf,
    const __hip_bfloat16* __restrict__ kbuf,
    const __hip_bfloat16* __restrict__ vtbuf,
    __hip_bfloat16* __restrict__ aout)
{
    __shared__ __align__(16) __bf16 kls[64*LSTRIDE];    // [key][feat]
    __shared__ __align__(16) __bf16 vls[64*VSTR];       // [d][key], 136B stride
    const int tid  = threadIdx.x;
    const int w    = tid >> 6;
    const int lane = tid & 63;
    const int quad = lane >> 4, low = lane & 15;
    const int id = blockIdx.x;
    const int bh = id % 96;
    const int qt = id / 96;
    const int b = bh / HEADS, h = bh % HEADS;
    const __bf16* qb = reinterpret_cast<const __bf16*>(qbuf);
    const __bf16* kb = reinterpret_cast<const __bf16*>(kbuf);
    const __bf16* vt = reinterpret_cast<const __bf16*>(vtbuf);
    const size_t base   = (size_t)bh * SEQ * HD;
    const size_t vtbase = (size_t)bh * HD * SEQP;
    const int q0 = qt*128 + w*32;

    int srow[2], sgk[2], soffk[2], soffv[2];
    #pragma unroll
    for (int i = 0; i < 2; ++i){
        int ch = tid + i*256;
        srow[i] = ch >> 3; sgk[i] = ch & 7;
        soffk[i] = srow[i]*LSTRIDE + sgk[i]*8;
        soffv[i] = srow[i]*VSTR    + sgk[i]*8;
    }

    bf16x8 bq[2][2];
    #pragma unroll
    for (int nt = 0; nt < 2; ++nt){
        int qs = q0 + nt*16 + low; if (qs > SEQ-1) qs = SEQ-1;
        #pragma unroll
        for (int ks = 0; ks < 2; ++ks)
            bq[nt][ks] = *reinterpret_cast<const bf16x8*>(qb + base + (size_t)qs*HD + ks*32 + quad*8);
    }

    bf16x8 kr[2], vr[2];
    #pragma unroll
    for (int i = 0; i < 2; ++i){
        int kk = srow[i]; if (kk > SEQ-1) kk = SEQ-1;
        kr[i] = *reinterpret_cast<const bf16x8*>(kb + base + (size_t)kk*HD + sgk[i]*8);
        vr[i] = *reinterpret_cast<const bf16x8*>(vt + vtbase + (size_t)srow[i]*SEQP + sgk[i]*8);
    }

    f32x4 o[2][4] = {};          // o[nt][dt]: row=q (quad*4+r), col=d (dt*16+low)
    float l_i[2] = {0.f, 0.f};

    for (int c = 0; c < NCHUNK; ++c){
        const int c0 = c*64;
        __syncthreads();
        #pragma unroll
        for (int i = 0; i < 2; ++i){
            *reinterpret_cast<bf16x8*>(&kls[soffk[i]]) = kr[i];
            bf16x4 vlo = __builtin_shufflevector(vr[i], vr[i], 0,1,2,3);
            bf16x4 vhi = __builtin_shufflevector(vr[i], vr[i], 4,5,6,7);
            *reinterpret_cast<bf16x4*>(&vls[soffv[i]])     = vlo;
            *reinterpret_cast<bf16x4*>(&vls[soffv[i] + 4]) = vhi;
        }
        __syncthreads();
        if (c + 1 < NCHUNK){
            const int c1 = c0 + 64;
            #pragma unroll
            for (int i = 0; i < 2; ++i){
                int kk = c1 + srow[i]; if (kk > SEQ-1) kk = SEQ-1;
                kr[i] = *reinterpret_cast<const bf16x8*>(kb + base + (size_t)kk*HD + sgk[i]*8);
                vr[i] = *reinterpret_cast<const bf16x8*>(vt + vtbase + (size_t)srow[i]*SEQP + c1 + sgk[i]*8);
            }
        }
        f32x4 st[4][2] = {};
        #pragma unroll
        for (int kt = 0; kt < 4; ++kt)
            #pragma unroll
            for (int ks = 0; ks < 2; ++ks){
                bf16x8 ak = *reinterpret_cast<const bf16x8*>(&kls[(kt*16 + low)*LSTRIDE + ks*32 + quad*8]);
                #pragma unroll
                for (int nt = 0; nt < 2; ++nt)
                    st[kt][nt] = MFMA_BF16(ak, bq[nt][ks], st[kt][nt]);
            }
        if (c0 + 64 > SEQ){
            #pragma unroll
            for (int kt = 0; kt < 4; ++kt)
                #pragma unroll
                for (int r = 0; r < 4; ++r){
                    int key = c0 + kt*16 + quad*4 + r;
                    if (key >= SEQ){ st[kt][0][r] = -1e30f; st[kt][1][r] = -1e30f; }
                }
        }
        // exp + in-lane l partial + pack P to bf16 A-fragments (in-register)
        s16x4 pa[4][2];
        #pragma unroll
        for (int nt = 0; nt < 2; ++nt)
            #pragma unroll
            for (int kt = 0; kt < 4; ++kt)
                #pragma unroll
                for (int r = 0; r < 4; ++r){
                    float p = __expf(st[kt][nt][r]);
                    l_i[nt] += p;
                    pa[kt][nt][r] = bfbits(p);
                }
        // O += P.V, A=P in-register, B=V from vls (conflict-free b64 reads)
        #pragma unroll
        for (int kt = 0; kt < 4; ++kt)
            #pragma unroll
            for (int dt = 0; dt < 4; ++dt){
                const s16x4 bv = *reinterpret_cast<const s16x4*>(&vls[(dt*16 + low)*VSTR + kt*16 + quad*4]);
                #pragma unroll
                for (int nt = 0; nt < 2; ++nt)
                    o[nt][dt] = MFMA16(pa[kt][nt], bv, o[nt][dt]);
            }
    }

    // reduce l across quads (lanes sharing 'low'), redistribute to output rows
    #pragma unroll
    for (int nt = 0; nt < 2; ++nt){
        l_i[nt] += __shfl_xor(l_i[nt], 16, 64);
        l_i[nt] += __shfl_xor(l_i[nt], 32, 64);
    }
    float lq[2][4];
    #pragma unroll
    for (int nt = 0; nt < 2; ++nt)
        #pragma unroll
        for (int r = 0; r < 4; ++r)
            lq[nt][r] = __shfl(l_i[nt], quad*4 + r, 64);

    #pragma unroll
    for (int nt = 0; nt < 2; ++nt)
        #pragma unroll
        for (int r = 0; r < 4; ++r){
            int s = q0 + nt*16 + quad*4 + r;
            if (s < SEQ){
                float inv = 1.0f / lq[nt][r];
                __hip_bfloat16* dst = aout + ((size_t)b*SEQ + s)*EMBED + h*HD;
                #pragma unroll
                for (int dt = 0; dt < 4; ++dt)
                    dst[dt*16 + low] = __float2bfloat16(o[nt][dt][r]*inv);
            }
        }
}

// out = attn @ Wo + bo. 64x128 tiles, 128 threads (2 waves x 64x64),
// grid (257, 3) = 771 blocks ~= 3.0/CU. m97-style double-buffered pipeline.
__global__ __launch_bounds__(128) void outproj_kernel(
    const __hip_bfloat16* __restrict__ a,
    const __hip_bfloat16* __restrict__ Wt,
    const float* __restrict__ bo,
    float* __restrict__ out)
{
    __shared__ __align__(16) __bf16 xs[2][64*32];
    __shared__ __align__(16) __bf16 bt[2][128*32];
    const int tid = threadIdx.x;          // 0..127
    const int m0 = blockIdx.x * 64;
    const int j  = blockIdx.y;
    const __bf16* ab = reinterpret_cast<const __bf16*>(a);
    const __bf16* wt = reinterpret_cast<const __bf16*>(Wt) + (size_t)3*EMBED*EMBED;

    const int w = tid >> 6;               // 0..1
    const int lane = tid & 63;
    const int quad = lane >> 4, low = lane & 15;
    const int rg = lane >> 2, cg = lane & 3;

    // A: 4 chunks of 16 rows; wave w stages chunks w*2, w*2+1
    int arow[2], aoff[2];
    #pragma unroll
    for (int i = 0; i < 2; ++i){
        int row = (w*2 + i)*16 + rg;
        int am = m0 + row; if (am > MTOT-1) am = MTOT-1;
        arow[i] = am;
        aoff[i] = (w*2 + i)*1024;
    }
    // B: 8 chunks of 16 rows; wave w stages chunks w*4 .. w*4+3
    int brow[4], boff[4];
    #pragma unroll
    for (int i = 0; i < 4; ++i){
        int row = (w*4 + i)*16 + rg;
        brow[i] = j*128 + row;
        boff[i] = (w*4 + i)*1024;
    }

    // prologue: stage tile 0 into buffer 0
    #pragma unroll
    for (int i = 0; i < 2; ++i)
        GLL16(ab + (size_t)arow[i]*EMBED + cg*8, (char*)xs[0] + aoff[i]);
    #pragma unroll
    for (int i = 0; i < 4; ++i)
        GLL16(wt + (size_t)brow[i]*EMBED + cg*8, (char*)bt[0] + boff[i]);
    __syncthreads();

    f32x4 acc[4][4] = {};
    for (int kb = 0; kb < 12; ++kb){
        const int cur = kb & 1;
        if (kb < 11){
            const int k1 = (kb+1)*32;
            #pragma unroll
            for (int i = 0; i < 2; ++i)
                GLL16(ab + (size_t)arow[i]*EMBED + k1 + cg*8, (char*)xs[cur^1] + aoff[i]);
            #pragma unroll
            for (int i = 0; i < 4; ++i)
                GLL16(wt + (size_t)brow[i]*EMBED + k1 + cg*8, (char*)bt[cur^1] + boff[i]);
        }
        bf16x8 af[4], bfr[4];
        #pragma unroll
        for (int mt = 0; mt < 4; ++mt)
            af[mt] = *reinterpret_cast<const bf16x8*>(&xs[cur][(mt*16 + low)*32 + quad*8]);
        #pragma unroll
        for (int t = 0; t < 4; ++t)
            bfr[t] = *reinterpret_cast<const bf16x8*>(&bt[cur][(w*64 + t*16 + low)*32 + quad*8]);
        #pragma unroll
        for (int t = 0; t < 4; ++t)
            #pragma unroll
            for (int mt = 0; mt < 4; ++mt)
                acc[mt][t] = MFMA_BF16(af[mt], bfr[t], acc[mt][t]);
        if (kb < 11) __syncthreads();
    }

    #pragma unroll
    for (int t = 0; t < 4; ++t){
        const int n = j*128 + w*64 + t*16 + low;
        const float bias = bo[n];
        #pragma unroll
        for (int mt = 0; mt < 4; ++mt)
            #pragma unroll
            for (int r = 0; r < 4; ++r){
                const int m = m0 + mt*16 + quad*4 + r;
                if (m < MTOT) out[(size_t)m*EMBED + n] = acc[mt][t][r] + bias;
            }
    }
}

extern "C" void kernel_launch(void* const* d_in, const int* in_sizes, int n_in,
                              void* d_out, int out_size, void* d_ws, size_t ws_size,
                              hipStream_t stream)
{
    const float* x  = (const float*)d_in[0];
    const float* Wq = (const float*)d_in[1];
    const float* Wk = (const float*)d_in[2];
    const float* Wv = (const float*)d_in[3];
    const float* Wo = (const float*)d_in[4];
    const float* bo = (const float*)d_in[5];
    float* out = (float*)d_out;

    // golden-ratio direction constants (exactly 10 cbrt iterations, as ref)
    double xd = 2.0;
    for (int it = 0; it < 10; ++it) xd = cbrt(1.0 + xd);
    float a1 = (float)(1.0 / xd);
    float a2 = a1 * a1;

    const size_t NE = (size_t)MTOT * EMBED;                 // 6,297,600
    const size_t VT = (size_t)BATCH*HEADS*HD*SEQP;          // padded V^T elems
    char* ws = (char*)d_ws;
    size_t off = 0;
    __hip_bfloat16* qbuf = (__hip_bfloat16*)(ws + off); off += 2*NE;
    __hip_bfloat16* kbuf = (__hip_bfloat16*)(ws + off); off += 2*NE;
    __hip_bfloat16* abuf = (__hip_bfloat16*)(ws + off); off += 2*NE;
    __hip_bfloat16* xbuf = (__hip_bfloat16*)(ws + off); off += 2*NE;
    __hip_bfloat16* vt   = (__hip_bfloat16*)(ws + off); off += 2*VT;
    __hip_bfloat16* Wt   = (__hip_bfloat16*)(ws + off); off += (size_t)4*EMBED*EMBED*2;
    float* cos_t = (float*)(ws + off); off += (size_t)SEQ*HEADS*NF*4;
    float* sin_t = (float*)(ws + off); off += (size_t)SEQ*HEADS*NF*4;

    prep_kernel<<<dim3(NB_X2B + NB_TW + NB_RT + NB_VF), dim3(256), 0, stream>>>(
        x, xbuf, Wq, Wk, Wv, Wo, Wt, cos_t, sin_t, vt, a1, a2);
    qkv_rope_kernel<<<dim3((MTOT + 127)/128, 9), dim3(256), 0, stream>>>(xbuf, Wt, cos_t, sin_t, qbuf, kbuf, vt);
    attn_kernel<<<dim3(864), dim3(256), 0, stream>>>(qbuf, kbuf, vt, abuf);
    outproj_kernel<<<dim3((MTOT + 63)/64, 3), dim3(128), 0, stream>>>(abuf, Wt, bo, out);
}

// Round 20
// 198.428 us; speedup vs baseline: 1.0325x; 1.0030x over previous
//
#include <hip/hip_runtime.h>
#include <hip/hip_bf16.h>
#include <math.h>

#define EMBED 384
#define HEADS 6
#define HD    64
#define NF    32
#define SEQ   1025
#define SEQP  1088   // padded key stride for Vt (17*64)
#define BATCH 16
#define MTOT  (BATCH*SEQ)   // 16400
#define NCHUNK 17
#define LSTRIDE 72   // attn K LDS row stride (elems)
#define VSTR   68    // attn V LDS row stride (elems): 136B -> conflict-free b64 reads
#define TSTR   66    // qkv epilogue transpose tile stride (2-way max conflicts)

// fused prep kernel block ranges
#define NB_X2B 6150                  // (MTOT*EMBED/4)/256
#define NB_TW  144                   // 6*6*4
#define NB_RT  769                   // ceil(SEQ*HEADS*NF/256)
#define NB_VF  192                   // vt tail zero-fill: 96*64 rows x 64 cols /8 /256

typedef __bf16 bf16x8 __attribute__((ext_vector_type(8)));
typedef __bf16 bf16x4 __attribute__((ext_vector_type(4)));
typedef float  f32x4  __attribute__((ext_vector_type(4)));
typedef short  s16x4  __attribute__((ext_vector_type(4)));

#define MFMA_BF16(A,B,C) __builtin_amdgcn_mfma_f32_16x16x32_bf16((A),(B),(C),0,0,0)
// K=16 bf16 MFMA (v_mfma_f32_16x16x16_bf16 on gfx950); A/B = short4 of bf16 bits
#define MFMA16(A,B,C) __builtin_amdgcn_mfma_f32_16x16x16bf16_1k((A),(B),(C),0,0,0)

// async global->LDS, 16B per lane: per-lane global src, wave-uniform LDS dest
#define GLL16(gp, lp) __builtin_amdgcn_global_load_lds( \
    (const __attribute__((address_space(1))) void*)(gp), \
    (__attribute__((address_space(3))) void*)(lp), 16, 0, 0)

__device__ __forceinline__ __bf16 f2bf(float f){
    __hip_bfloat16 h = __float2bfloat16(f);
    return *reinterpret_cast<__bf16*>(&h);
}
__device__ __forceinline__ short bfbits(float f){
    __hip_bfloat16 h = __float2bfloat16(f);
    return *reinterpret_cast<short*>(&h);
}

// fp32 erfinv (Giles 2010)
__device__ __forceinline__ float erfinv_f(float x){
    float w = -log1pf(-x*x);
    float p;
    if (w < 5.0f){
        w -= 2.5f;
        p = 2.81022636e-08f;
        p = fmaf(p, w, 3.43273939e-07f);
        p = fmaf(p, w, -3.5233877e-06f);
        p = fmaf(p, w, -4.39150654e-06f);
        p = fmaf(p, w, 0.00021858087f);
        p = fmaf(p, w, -0.00125372503f);
        p = fmaf(p, w, -0.00417768164f);
        p = fmaf(p, w, 0.246640727f);
        p = fmaf(p, w, 1.50140941f);
    } else {
        w = sqrtf(w) - 3.0f;
        p = -0.000200214257f;
        p = fmaf(p, w, 0.000100950558f);
        p = fmaf(p, w, 0.00134934322f);
        p = fmaf(p, w, -0.00367342844f);
        p = fmaf(p, w, 0.00573950773f);
        p = fmaf(p, w, -0.0076224613f);
        p = fmaf(p, w, 0.00943887047f);
        p = fmaf(p, w, 1.00167406f);
        p = fmaf(p, w, 2.83297682f);
    }
    return p * x;
}

// -------- fused prep: x->bf16 | W transpose | rope tables | vt tail fill ----
// a1/a2 (golden-ratio direction base) computed on HOST.
__global__ __launch_bounds__(256) void prep_kernel(
    const float* __restrict__ x, __hip_bfloat16* __restrict__ xb,
    const float* __restrict__ Wq, const float* __restrict__ Wk,
    const float* __restrict__ Wv, const float* __restrict__ Wo,
    __hip_bfloat16* __restrict__ Wt,
    float* __restrict__ cos_t, float* __restrict__ sin_t,
    __hip_bfloat16* __restrict__ vt,
    float a1, float a2)
{
    __shared__ float tile[64][65];
    const int bid = blockIdx.x;
    const int tid = threadIdx.x;

    if (bid < NB_X2B){
        // ---- x fp32 -> bf16 ----
        int i = bid*256 + tid;                  // < 1,574,400 always
        float4 v = *reinterpret_cast<const float4*>(x + (size_t)i*4);
        bf16x4 b; b[0]=f2bf(v.x); b[1]=f2bf(v.y); b[2]=f2bf(v.z); b[3]=f2bf(v.w);
        *reinterpret_cast<bf16x4*>(reinterpret_cast<__bf16*>(xb) + (size_t)i*4) = b;
        return;
    }
    if (bid < NB_X2B + NB_TW){
        // ---- weight transpose: W fp32 [k][n] -> Wt bf16 [mat][n][k] ----
        int idx = bid - NB_X2B;                 // 0..143
        const int mat = idx / 36;
        const int rem = idx % 36;
        const int kx = rem / 6, ny = rem % 6;
        const float* W = (mat==0)?Wq:(mat==1)?Wk:(mat==2)?Wv:Wo;
        const int k0 = kx*64, n0 = ny*64;
        const int c = tid & 63, rq = tid >> 6;
        #pragma unroll
        for (int i = 0; i < 16; ++i){
            int row = rq*16 + i;
            tile[row][c] = W[(size_t)(k0+row)*EMBED + n0 + c];
        }
        __syncthreads();
        #pragma unroll
        for (int i = 0; i < 16; ++i){
            int nr = rq*16 + i;
            Wt[((size_t)mat*EMBED + n0 + nr)*EMBED + k0 + c] = __float2bfloat16(tile[c][nr]);
        }
        return;
    }
    if (bid < NB_X2B + NB_TW + NB_RT){
        // ---- rope tables (constants hoisted to host) ----
        int idx = (bid - NB_X2B - NB_TW)*256 + tid;
        if (idx >= SEQ*HEADS*NF) return;
        int f  = idx & (NF-1);
        int hf = idx / NF;
        int h  = hf % HEADS;
        int s  = hf / HEADS;

        float fi = (float)(h*NF + f + 1);
        float z1 = fmodf(fi * a1, 1.0f);
        float z2 = fmodf(fi * a2, 1.0f);
        float d1 = erfinv_f(2.0f*z1 - 1.0f);
        float d2 = erfinv_f(2.0f*z2 - 1.0f);
        float inv = 1.0f / sqrtf(d1*d1 + d2*d2);
        d1 *= inv; d2 *= inv;

        float omega = 0.1f * powf(10000.0f, (float)f / 31.0f);
        float fx = d1 * omega, fy = d2 * omega;

        float cx = 0.0f, cy = 0.0f;
        if (s > 0){
            int pi = s - 1;
            cx = (float)(pi & 31) / 31.0f * 2.0f - 1.0f;
            cy = (float)(pi >> 5) / 31.0f * 2.0f - 1.0f;
        }
        float theta = fx*cx + fy*cy;
        float sv, cv;
        sincosf(theta, &sv, &cv);
        cos_t[idx] = cv;
        sin_t[idx] = sv;
        return;
    }
    // ---- vt tail zero-fill: cols 1024..1087 of all 96*64 rows ----
    {
        int g = (bid - NB_X2B - NB_TW - NB_RT)*256 + tid;   // < 49152 exact
        int row = g >> 3, sg = g & 7;
        bf16x8 z = {};
        *reinterpret_cast<bf16x8*>(reinterpret_cast<__bf16*>(vt)
            + (size_t)row*SEQP + 1024 + sg*8) = z;
    }
}

// QKV: one big GEMM xb[16400x384] @ Wt[1152x384]^T, 128x128 tiles.
// grid (129, 9), block 256 (4 waves, 2x2). Wave = 64 rows x one head's 64 cols.
// m97-style pipeline: double-buffered LDS via global_load_lds width=16.
// Epilogue: RoPE for q/k; V^T written DIRECTLY (LDS transpose through the
// dead tile buffers).
__global__ __launch_bounds__(256, 3) void qkv_rope_kernel(
    const __hip_bfloat16* __restrict__ xb_,
    const __hip_bfloat16* __restrict__ Wt,
    const float* __restrict__ cos_t,
    const float* __restrict__ sin_t,
    __hip_bfloat16* __restrict__ qbuf,
    __hip_bfloat16* __restrict__ kbuf,
    __hip_bfloat16* __restrict__ vtbuf)
{
    __shared__ __align__(16) __bf16 smem[16384];   // 32KB: xs dbuf + bt dbuf
    const int tid = threadIdx.x;
    const int m0 = blockIdx.x * 128;
    const int j  = blockIdx.y;
    const __bf16* xb = reinterpret_cast<const __bf16*>(xb_);
    const __bf16* wt = reinterpret_cast<const __bf16*>(Wt);
    __bf16* vtb = reinterpret_cast<__bf16*>(vtbuf);

    const int w = tid >> 6;
    const int lane = tid & 63;
    const int quad = lane >> 4, low = lane & 15;
    const int rg = lane >> 2, cg = lane & 3;   // 16 rows x 4 granules per chunk

    // wave w stages chunks w*2, w*2+1 (16 rows each) of both A and B
    int arow[2], brow[2], loff[2];
    #pragma unroll
    for (int i = 0; i < 2; ++i){
        int row = (w*2 + i)*16 + rg;
        int am = m0 + row; if (am > MTOT-1) am = MTOT-1;
        arow[i] = am;
        brow[i] = j*128 + row;          // < 1152 always
        loff[i] = (w*2 + i)*1024;       // bytes: 16 rows x 64B
    }

    // prologue: stage tile 0 into buffer 0 (xs at smem[0], bt at smem[8192])
    #pragma unroll
    for (int i = 0; i < 2; ++i){
        GLL16(xb + (size_t)arow[i]*EMBED + cg*8, (char*)smem + loff[i]);
        GLL16(wt + (size_t)brow[i]*EMBED + cg*8, (char*)(smem + 8192) + loff[i]);
    }
    __syncthreads();

    const int mh = w >> 1, nh = w & 1;
    const int mw0 = m0 + mh*64;

    f32x4 acc[4][4] = {};
    for (int kb = 0; kb < 12; ++kb){
        const int cur = kb & 1;
        const __bf16* xcur = smem + cur*4096;
        const __bf16* bcur = smem + 8192 + cur*4096;
        // issue tile k+1's loads into the alternate buffer (fly over compute)
        if (kb < 11){
            const int k1 = (kb+1)*32;
            __bf16* xnxt = smem + (cur^1)*4096;
            __bf16* bnxt = smem + 8192 + (cur^1)*4096;
            #pragma unroll
            for (int i = 0; i < 2; ++i){
                GLL16(xb + (size_t)arow[i]*EMBED + k1 + cg*8, (char*)xnxt + loff[i]);
                GLL16(wt + (size_t)brow[i]*EMBED + k1 + cg*8, (char*)bnxt + loff[i]);
            }
        }
        bf16x8 af[4], bfr[4];
        #pragma unroll
        for (int mt = 0; mt < 4; ++mt)
            af[mt] = *reinterpret_cast<const bf16x8*>(&xcur[(mh*64 + mt*16 + low)*32 + quad*8]);
        #pragma unroll
        for (int t = 0; t < 4; ++t)
            bfr[t] = *reinterpret_cast<const bf16x8*>(&bcur[(nh*64 + t*16 + low)*32 + quad*8]);
        #pragma unroll
        for (int t = 0; t < 4; ++t)
            #pragma unroll
            for (int mt = 0; mt < 4; ++mt)
                acc[mt][t] = MFMA_BF16(af[mt], bfr[t], acc[mt][t]);
        if (kb < 11) __syncthreads();   // drains vmcnt(0): tile k+1 landed
    }

    const int n64 = j*2 + nh;           // 0..17
    const int mat = n64 / 6;            // j-uniform (2j and 2j+1 share mat)
    const int h   = n64 % 6;

    if (mat == 2){
        // ---- V^T direct store via LDS transpose (block-uniform branch) ----
        __syncthreads();                // main-loop LDS reads done
        const int d8 = lane >> 3, sg = lane & 7;
        const int m0c = mw0 + sg*8;
        const int b0 = m0c / SEQ;
        const int s0 = m0c - b0*SEQ;
        const bool fast = (m0c + 7 < MTOT) && (s0 + 7 < SEQ);
        #pragma unroll
        for (int ph = 0; ph < 2; ++ph){
            if (mh == ph){
                __bf16* tl = smem + nh*4608;       // 64 x TSTR(66)
                #pragma unroll
                for (int mt = 0; mt < 4; ++mt)
                    #pragma unroll
                    for (int t = 0; t < 4; ++t)
                        #pragma unroll
                        for (int r = 0; r < 4; ++r)
                            tl[(mt*16 + quad*4 + r)*TSTR + t*16 + low] = f2bf(acc[mt][t][r]);
            }
            __syncthreads();
            if (mh == ph){
                __bf16* tl = smem + nh*4608;
                #pragma unroll
                for (int db = 0; db < 8; ++db){
                    const int d = db*8 + d8;
                    if (fast){
                        bf16x8 val;
                        #pragma unroll
                        for (int e = 0; e < 8; ++e) val[e] = tl[(sg*8+e)*TSTR + d];
                        *reinterpret_cast<bf16x8*>(
                            vtb + ((size_t)(b0*HEADS + h)*HD + d)*SEQP + s0) = val;
                    } else {
                        #pragma unroll
                        for (int e = 0; e < 8; ++e){
                            int m = m0c + e;
                            if (m < MTOT){
                                int bb = m / SEQ, ss = m - bb*SEQ;
                                vtb[((size_t)(bb*HEADS + h)*HD + d)*SEQP + ss] =
                                    tl[(sg*8+e)*TSTR + d];
                            }
                        }
                    }
                }
            }
            __syncthreads();
        }
    } else {
        __hip_bfloat16* ob = (mat == 0) ? qbuf : kbuf;
        const float qs_ = (mat == 0) ? 0.125f : 1.0f;
        #pragma unroll
        for (int mt = 0; mt < 4; ++mt)
            #pragma unroll
            for (int t = 0; t < 2; ++t)
                #pragma unroll
                for (int r = 0; r < 4; ++r){
                    int m = mw0 + mt*16 + quad*4 + r;
                    if (m < MTOT){
                        int b = m / SEQ, s = m % SEQ;
                        int f = t*16 + low;
                        float cv = cos_t[(s*HEADS + h)*NF + f];
                        float sv = sin_t[(s*HEADS + h)*NF + f];
                        float x1 = acc[mt][t][r];
                        float y1 = acc[mt][t+2][r];
                        size_t base = ((size_t)(b*HEADS + h)*SEQ + s)*HD;
                        ob[base + f]      = __float2bfloat16((x1*cv - y1*sv)*qs_);
                        ob[base + NF + f] = __float2bfloat16((x1*sv + y1*cv)*qs_);
                    }
                }
    }
}

// Flash attention, fixed-base softmax (no running max: scores bounded ~|5|).
// S^T = K.Q^T (qrow in-lane). PV = P.V via 16x16x16 MFMA with P in registers.
// T1: XCD-aware block swizzle (864 = 8 XCD x 108): each XCD owns 12 bh ->
// K/V+Vt working set 3.2MB stays resident in its 4MB L2 across all 9 q-tiles.
__global__ __launch_bounds__(256, 4) void attn_kernel(
    const __hip_bfloat16* __restrict__ qbuf,
    const __hip_bfloat16* __restrict__ kbuf,
    const __hip_bfloat16* __restrict__ vtbuf,
    __hip_bfloat16* __restrict__ aout)
{
    __shared__ __align__(16) __bf16 kls[64*LSTRIDE];    // [key][feat]
    __shared__ __align__(16) __bf16 vls[64*VSTR];       // [d][key], 136B stride
    const int tid  = threadIdx.x;
    const int w    = tid >> 6;
    const int lane = tid & 63;
    const int quad = lane >> 4, low = lane & 15;
    const int id = blockIdx.x;
    const int xcd = id & 7, sl = id >> 3;   // 108 slots per XCD
    const int bh = xcd*12 + sl/9;           // 12 bh pinned per XCD
    const int qt = sl % 9;
    const int b = bh / HEADS, h = bh % HEADS;
    const __bf16* qb = reinterpret_cast<const __bf16*>(qbuf);
    const __bf16* kb = reinterpret_cast<const __bf16*>(kbuf);
    const __bf16* vt = reinterpret_cast<const __bf16*>(vtbuf);
    const size_t base   = (size_t)bh * SEQ * HD;
    const size_t vtbase = (size_t)bh * HD * SEQP;
    const int q0 = qt*128 + w*32;

    int srow[2], sgk[2], soffk[2], soffv[2];
    #pragma unroll
    for (int i = 0; i < 2; ++i){
        int ch = tid + i*256;
        srow[i] = ch >> 3; sgk[i] = ch & 7;
        soffk[i] = srow[i]*LSTRIDE + sgk[i]*8;
        soffv[i] = srow[i]*VSTR    + sgk[i]*8;
    }

    bf16x8 bq[2][2];
    #pragma unroll
    for (int nt = 0; nt < 2; ++nt){
        int qs = q0 + nt*16 + low; if (qs > SEQ-1) qs = SEQ-1;
        #pragma unroll
        for (int ks = 0; ks < 2; ++ks)
            bq[nt][ks] = *reinterpret_cast<const bf16x8*>(qb + base + (size_t)qs*HD + ks*32 + quad*8);
    }

    bf16x8 kr[2], vr[2];
    #pragma unroll
    for (int i = 0; i < 2; ++i){
        int kk = srow[i]; if (kk > SEQ-1) kk = SEQ-1;
        kr[i] = *reinterpret_cast<const bf16x8*>(kb + base + (size_t)kk*HD + sgk[i]*8);
        vr[i] = *reinterpret_cast<const bf16x8*>(vt + vtbase + (size_t)srow[i]*SEQP + sgk[i]*8);
    }

    f32x4 o[2][4] = {};          // o[nt][dt]: row=q (quad*4+r), col=d (dt*16+low)
    float l_i[2] = {0.f, 0.f};

    for (int c = 0; c < NCHUNK; ++c){
        const int c0 = c*64;
        __syncthreads();
        #pragma unroll
        for (int i = 0; i < 2; ++i){
            *reinterpret_cast<bf16x8*>(&kls[soffk[i]]) = kr[i];
            bf16x4 vlo = __builtin_shufflevector(vr[i], vr[i], 0,1,2,3);
            bf16x4 vhi = __builtin_shufflevector(vr[i], vr[i], 4,5,6,7);
            *reinterpret_cast<bf16x4*>(&vls[soffv[i]])     = vlo;
            *reinterpret_cast<bf16x4*>(&vls[soffv[i] + 4]) = vhi;
        }
        __syncthreads();
        if (c + 1 < NCHUNK){
            const int c1 = c0 + 64;
            #pragma unroll
            for (int i = 0; i < 2; ++i){
                int kk = c1 + srow[i]; if (kk > SEQ-1) kk = SEQ-1;
                kr[i] = *reinterpret_cast<const bf16x8*>(kb + base + (size_t)kk*HD + sgk[i]*8);
                vr[i] = *reinterpret_cast<const bf16x8*>(vt + vtbase + (size_t)srow[i]*SEQP + c1 + sgk[i]*8);
            }
        }
        f32x4 st[4][2] = {};
        #pragma unroll
        for (int kt = 0; kt < 4; ++kt)
            #pragma unroll
            for (int ks = 0; ks < 2; ++ks){
                bf16x8 ak = *reinterpret_cast<const bf16x8*>(&kls[(kt*16 + low)*LSTRIDE + ks*32 + quad*8]);
                #pragma unroll
                for (int nt = 0; nt < 2; ++nt)
                    st[kt][nt] = MFMA_BF16(ak, bq[nt][ks], st[kt][nt]);
            }
        if (c0 + 64 > SEQ){
            #pragma unroll
            for (int kt = 0; kt < 4; ++kt)
                #pragma unroll
                for (int r = 0; r < 4; ++r){
                    int key = c0 + kt*16 + quad*4 + r;
                    if (key >= SEQ){ st[kt][0][r] = -1e30f; st[kt][1][r] = -1e30f; }
                }
        }
        // exp + in-lane l partial + pack P to bf16 A-fragments (in-register)
        s16x4 pa[4][2];
        #pragma unroll
        for (int nt = 0; nt < 2; ++nt)
            #pragma unroll
            for (int kt = 0; kt < 4; ++kt)
                #pragma unroll
                for (int r = 0; r < 4; ++r){
                    float p = __expf(st[kt][nt][r]);
                    l_i[nt] += p;
                    pa[kt][nt][r] = bfbits(p);
                }
        // O += P.V, A=P in-register, B=V from vls (conflict-free b64 reads)
        #pragma unroll
        for (int kt = 0; kt < 4; ++kt)
            #pragma unroll
            for (int dt = 0; dt < 4; ++dt){
                const s16x4 bv = *reinterpret_cast<const s16x4*>(&vls[(dt*16 + low)*VSTR + kt*16 + quad*4]);
                #pragma unroll
                for (int nt = 0; nt < 2; ++nt)
                    o[nt][dt] = MFMA16(pa[kt][nt], bv, o[nt][dt]);
            }
    }

    // reduce l across quads (lanes sharing 'low'), redistribute to output rows
    #pragma unroll
    for (int nt = 0; nt < 2; ++nt){
        l_i[nt] += __shfl_xor(l_i[nt], 16, 64);
        l_i[nt] += __shfl_xor(l_i[nt], 32, 64);
    }
    float lq[2][4];
    #pragma unroll
    for (int nt = 0; nt < 2; ++nt)
        #pragma unroll
        for (int r = 0; r < 4; ++r)
            lq[nt][r] = __shfl(l_i[nt], quad*4 + r, 64);

    #pragma unroll
    for (int nt = 0; nt < 2; ++nt)
        #pragma unroll
        for (int r = 0; r < 4; ++r){
            int s = q0 + nt*16 + quad*4 + r;
            if (s < SEQ){
                float inv = 1.0f / lq[nt][r];
                __hip_bfloat16* dst = aout + ((size_t)b*SEQ + s)*EMBED + h*HD;
                #pragma unroll
                for (int dt = 0; dt < 4; ++dt)
                    dst[dt*16 + low] = __float2bfloat16(o[nt][dt][r]*inv);
            }
        }
}

// out = attn @ Wo + bo. 64x128 tiles, 128 threads (2 waves x 64x64),
// grid (257, 3) = 771 blocks ~= 3.0/CU. m97-style double-buffered pipeline.
__global__ __launch_bounds__(128) void outproj_kernel(
    const __hip_bfloat16* __restrict__ a,
    const __hip_bfloat16* __restrict__ Wt,
    const float* __restrict__ bo,
    float* __restrict__ out)
{
    __shared__ __align__(16) __bf16 xs[2][64*32];
    __shared__ __align__(16) __bf16 bt[2][128*32];
    const int tid = threadIdx.x;          // 0..127
    const int m0 = blockIdx.x * 64;
    const int j  = blockIdx.y;
    const __bf16* ab = reinterpret_cast<const __bf16*>(a);
    const __bf16* wt = reinterpret_cast<const __bf16*>(Wt) + (size_t)3*EMBED*EMBED;

    const int w = tid >> 6;               // 0..1
    const int lane = tid & 63;
    const int quad = lane >> 4, low = lane & 15;
    const int rg = lane >> 2, cg = lane & 3;

    // A: 4 chunks of 16 rows; wave w stages chunks w*2, w*2+1
    int arow[2], aoff[2];
    #pragma unroll
    for (int i = 0; i < 2; ++i){
        int row = (w*2 + i)*16 + rg;
        int am = m0 + row; if (am > MTOT-1) am = MTOT-1;
        arow[i] = am;
        aoff[i] = (w*2 + i)*1024;
    }
    // B: 8 chunks of 16 rows; wave w stages chunks w*4 .. w*4+3
    int brow[4], boff[4];
    #pragma unroll
    for (int i = 0; i < 4; ++i){
        int row = (w*4 + i)*16 + rg;
        brow[i] = j*128 + row;
        boff[i] = (w*4 + i)*1024;
    }

    // prologue: stage tile 0 into buffer 0
    #pragma unroll
    for (int i = 0; i < 2; ++i)
        GLL16(ab + (size_t)arow[i]*EMBED + cg*8, (char*)xs[0] + aoff[i]);
    #pragma unroll
    for (int i = 0; i < 4; ++i)
        GLL16(wt + (size_t)brow[i]*EMBED + cg*8, (char*)bt[0] + boff[i]);
    __syncthreads();

    f32x4 acc[4][4] = {};
    for (int kb = 0; kb < 12; ++kb){
        const int cur = kb & 1;
        if (kb < 11){
            const int k1 = (kb+1)*32;
            #pragma unroll
            for (int i = 0; i < 2; ++i)
                GLL16(ab + (size_t)arow[i]*EMBED + k1 + cg*8, (char*)xs[cur^1] + aoff[i]);
            #pragma unroll
            for (int i = 0; i < 4; ++i)
                GLL16(wt + (size_t)brow[i]*EMBED + k1 + cg*8, (char*)bt[cur^1] + boff[i]);
        }
        bf16x8 af[4], bfr[4];
        #pragma unroll
        for (int mt = 0; mt < 4; ++mt)
            af[mt] = *reinterpret_cast<const bf16x8*>(&xs[cur][(mt*16 + low)*32 + quad*8]);
        #pragma unroll
        for (int t = 0; t < 4; ++t)
            bfr[t] = *reinterpret_cast<const bf16x8*>(&bt[cur][(w*64 + t*16 + low)*32 + quad*8]);
        #pragma unroll
        for (int t = 0; t < 4; ++t)
            #pragma unroll
            for (int mt = 0; mt < 4; ++mt)
                acc[mt][t] = MFMA_BF16(af[mt], bfr[t], acc[mt][t]);
        if (kb < 11) __syncthreads();
    }

    #pragma unroll
    for (int t = 0; t < 4; ++t){
        const int n = j*128 + w*64 + t*16 + low;
        const float bias = bo[n];
        #pragma unroll
        for (int mt = 0; mt < 4; ++mt)
            #pragma unroll
            for (int r = 0; r < 4; ++r){
                const int m = m0 + mt*16 + quad*4 + r;
                if (m < MTOT) out[(size_t)m*EMBED + n] = acc[mt][t][r] + bias;
            }
    }
}

extern "C" void kernel_launch(void* const* d_in, const int* in_sizes, int n_in,
                              void* d_out, int out_size, void* d_ws, size_t ws_size,
                              hipStream_t stream)
{
    const float* x  = (const float*)d_in[0];
    const float* Wq = (const float*)d_in[1];
    const float* Wk = (const float*)d_in[2];
    const float* Wv = (const float*)d_in[3];
    const float* Wo = (const float*)d_in[4];
    const float* bo = (const float*)d_in[5];
    float* out = (float*)d_out;

    // golden-ratio direction constants (exactly 10 cbrt iterations, as ref)
    double xd = 2.0;
    for (int it = 0; it < 10; ++it) xd = cbrt(1.0 + xd);
    float a1 = (float)(1.0 / xd);
    float a2 = a1 * a1;

    const size_t NE = (size_t)MTOT * EMBED;                 // 6,297,600
    const size_t VT = (size_t)BATCH*HEADS*HD*SEQP;          // padded V^T elems
    char* ws = (char*)d_ws;
    size_t off = 0;
    __hip_bfloat16* qbuf = (__hip_bfloat16*)(ws + off); off += 2*NE;
    __hip_bfloat16* kbuf = (__hip_bfloat16*)(ws + off); off += 2*NE;
    __hip_bfloat16* abuf = (__hip_bfloat16*)(ws + off); off += 2*NE;
    __hip_bfloat16* xbuf = (__hip_bfloat16*)(ws + off); off += 2*NE;
    __hip_bfloat16* vt   = (__hip_bfloat16*)(ws + off); off += 2*VT;
    __hip_bfloat16* Wt   = (__hip_bfloat16*)(ws + off); off += (size_t)4*EMBED*EMBED*2;
    float* cos_t = (float*)(ws + off); off += (size_t)SEQ*HEADS*NF*4;
    float* sin_t = (float*)(ws + off); off += (size_t)SEQ*HEADS*NF*4;

    prep_kernel<<<dim3(NB_X2B + NB_TW + NB_RT + NB_VF), dim3(256), 0, stream>>>(
        x, xbuf, Wq, Wk, Wv, Wo, Wt, cos_t, sin_t, vt, a1, a2);
    qkv_rope_kernel<<<dim3((MTOT + 127)/128, 9), dim3(256), 0, stream>>>(xbuf, Wt, cos_t, sin_t, qbuf, kbuf, vt);
    attn_kernel<<<dim3(864), dim3(256), 0, stream>>>(qbuf, kbuf, vt, abuf);
    outproj_kernel<<<dim3((MTOT + 63)/64, 3), dim3(128), 0, stream>>>(abuf, Wt, bo, out);
}

// Round 21
// 195.902 us; speedup vs baseline: 1.0458x; 1.0129x over previous
//
#include <hip/hip_runtime.h>
#include <hip/hip_bf16.h>
#include <math.h>

#define EMBED 384
#define HEADS 6
#define HD    64
#define NF    32
#define SEQ   1025
#define SEQP  1088   // padded key stride for Vt (17*64)
#define BATCH 16
#define MTOT  (BATCH*SEQ)   // 16400
#define NCHUNK 17
#define LSTRIDE 72   // attn K LDS row stride (elems)
#define VSTR   68    // attn V LDS row stride (elems): 136B -> conflict-free b64 reads
#define TSTR   66    // qkv epilogue transpose tile stride (2-way max conflicts)

// fused prep kernel block ranges
#define NB_X2B 6150                  // (MTOT*EMBED/4)/256
#define NB_TW  144                   // 6*6*4
#define NB_RT  769                   // ceil(SEQ*HEADS*NF/256)
#define NB_VF  192                   // vt tail zero-fill: 96*64 rows x 64 cols /8 /256

typedef __bf16 bf16x8 __attribute__((ext_vector_type(8)));
typedef __bf16 bf16x4 __attribute__((ext_vector_type(4)));
typedef float  f32x4  __attribute__((ext_vector_type(4)));
typedef short  s16x4  __attribute__((ext_vector_type(4)));

#define MFMA_BF16(A,B,C) __builtin_amdgcn_mfma_f32_16x16x32_bf16((A),(B),(C),0,0,0)
// K=16 bf16 MFMA (v_mfma_f32_16x16x16_bf16 on gfx950); A/B = short4 of bf16 bits
#define MFMA16(A,B,C) __builtin_amdgcn_mfma_f32_16x16x16bf16_1k((A),(B),(C),0,0,0)

// async global->LDS, 16B per lane: per-lane global src, wave-uniform LDS dest
#define GLL16(gp, lp) __builtin_amdgcn_global_load_lds( \
    (const __attribute__((address_space(1))) void*)(gp), \
    (__attribute__((address_space(3))) void*)(lp), 16, 0, 0)

__device__ __forceinline__ __bf16 f2bf(float f){
    __hip_bfloat16 h = __float2bfloat16(f);
    return *reinterpret_cast<__bf16*>(&h);
}
__device__ __forceinline__ short bfbits(float f){
    __hip_bfloat16 h = __float2bfloat16(f);
    return *reinterpret_cast<short*>(&h);
}

// fp32 erfinv (Giles 2010)
__device__ __forceinline__ float erfinv_f(float x){
    float w = -log1pf(-x*x);
    float p;
    if (w < 5.0f){
        w -= 2.5f;
        p = 2.81022636e-08f;
        p = fmaf(p, w, 3.43273939e-07f);
        p = fmaf(p, w, -3.5233877e-06f);
        p = fmaf(p, w, -4.39150654e-06f);
        p = fmaf(p, w, 0.00021858087f);
        p = fmaf(p, w, -0.00125372503f);
        p = fmaf(p, w, -0.00417768164f);
        p = fmaf(p, w, 0.246640727f);
        p = fmaf(p, w, 1.50140941f);
    } else {
        w = sqrtf(w) - 3.0f;
        p = -0.000200214257f;
        p = fmaf(p, w, 0.000100950558f);
        p = fmaf(p, w, 0.00134934322f);
        p = fmaf(p, w, -0.00367342844f);
        p = fmaf(p, w, 0.00573950773f);
        p = fmaf(p, w, -0.0076224613f);
        p = fmaf(p, w, 0.00943887047f);
        p = fmaf(p, w, 1.00167406f);
        p = fmaf(p, w, 2.83297682f);
    }
    return p * x;
}

// -------- fused prep: x->bf16 | W transpose | rope tables | vt tail fill ----
// a1/a2 (golden-ratio direction base) computed on HOST.
__global__ __launch_bounds__(256) void prep_kernel(
    const float* __restrict__ x, __hip_bfloat16* __restrict__ xb,
    const float* __restrict__ Wq, const float* __restrict__ Wk,
    const float* __restrict__ Wv, const float* __restrict__ Wo,
    __hip_bfloat16* __restrict__ Wt,
    float* __restrict__ cos_t, float* __restrict__ sin_t,
    __hip_bfloat16* __restrict__ vt,
    float a1, float a2)
{
    __shared__ float tile[64][65];
    const int bid = blockIdx.x;
    const int tid = threadIdx.x;

    if (bid < NB_X2B){
        // ---- x fp32 -> bf16 ----
        int i = bid*256 + tid;                  // < 1,574,400 always
        float4 v = *reinterpret_cast<const float4*>(x + (size_t)i*4);
        bf16x4 b; b[0]=f2bf(v.x); b[1]=f2bf(v.y); b[2]=f2bf(v.z); b[3]=f2bf(v.w);
        *reinterpret_cast<bf16x4*>(reinterpret_cast<__bf16*>(xb) + (size_t)i*4) = b;
        return;
    }
    if (bid < NB_X2B + NB_TW){
        // ---- weight transpose: W fp32 [k][n] -> Wt bf16 [mat][n][k] ----
        int idx = bid - NB_X2B;                 // 0..143
        const int mat = idx / 36;
        const int rem = idx % 36;
        const int kx = rem / 6, ny = rem % 6;
        const float* W = (mat==0)?Wq:(mat==1)?Wk:(mat==2)?Wv:Wo;
        const int k0 = kx*64, n0 = ny*64;
        const int c = tid & 63, rq = tid >> 6;
        #pragma unroll
        for (int i = 0; i < 16; ++i){
            int row = rq*16 + i;
            tile[row][c] = W[(size_t)(k0+row)*EMBED + n0 + c];
        }
        __syncthreads();
        #pragma unroll
        for (int i = 0; i < 16; ++i){
            int nr = rq*16 + i;
            Wt[((size_t)mat*EMBED + n0 + nr)*EMBED + k0 + c] = __float2bfloat16(tile[c][nr]);
        }
        return;
    }
    if (bid < NB_X2B + NB_TW + NB_RT){
        // ---- rope tables (constants hoisted to host) ----
        int idx = (bid - NB_X2B - NB_TW)*256 + tid;
        if (idx >= SEQ*HEADS*NF) return;
        int f  = idx & (NF-1);
        int hf = idx / NF;
        int h  = hf % HEADS;
        int s  = hf / HEADS;

        float fi = (float)(h*NF + f + 1);
        float z1 = fmodf(fi * a1, 1.0f);
        float z2 = fmodf(fi * a2, 1.0f);
        float d1 = erfinv_f(2.0f*z1 - 1.0f);
        float d2 = erfinv_f(2.0f*z2 - 1.0f);
        float inv = 1.0f / sqrtf(d1*d1 + d2*d2);
        d1 *= inv; d2 *= inv;

        float omega = 0.1f * powf(10000.0f, (float)f / 31.0f);
        float fx = d1 * omega, fy = d2 * omega;

        float cx = 0.0f, cy = 0.0f;
        if (s > 0){
            int pi = s - 1;
            cx = (float)(pi & 31) / 31.0f * 2.0f - 1.0f;
            cy = (float)(pi >> 5) / 31.0f * 2.0f - 1.0f;
        }
        float theta = fx*cx + fy*cy;
        float sv, cv;
        sincosf(theta, &sv, &cv);
        cos_t[idx] = cv;
        sin_t[idx] = sv;
        return;
    }
    // ---- vt tail zero-fill: cols 1024..1087 of all 96*64 rows ----
    {
        int g = (bid - NB_X2B - NB_TW - NB_RT)*256 + tid;   // < 49152 exact
        int row = g >> 3, sg = g & 7;
        bf16x8 z = {};
        *reinterpret_cast<bf16x8*>(reinterpret_cast<__bf16*>(vt)
            + (size_t)row*SEQP + 1024 + sg*8) = z;
    }
}

// QKV: one big GEMM xb[16400x384] @ Wt[1152x384]^T, 128x128 tiles.
// 1D grid 1161 with bijective XCD swizzle (q=145,r=1): each XCD owns ~16
// m-blocks ACROSS ALL 9 j -> its A-slice (1.6MB) + Wt (0.85MB) stay L2-
// resident, converting the 8x A re-reads from HBM (~900cy) to L2 (~200cy).
// m97-style pipeline: double-buffered LDS via global_load_lds width=16.
// Epilogue: RoPE for q/k; V^T written directly via LDS transpose.
__global__ __launch_bounds__(256, 3) void qkv_rope_kernel(
    const __hip_bfloat16* __restrict__ xb_,
    const __hip_bfloat16* __restrict__ Wt,
    const float* __restrict__ cos_t,
    const float* __restrict__ sin_t,
    __hip_bfloat16* __restrict__ qbuf,
    __hip_bfloat16* __restrict__ kbuf,
    __hip_bfloat16* __restrict__ vtbuf)
{
    __shared__ __align__(16) __bf16 smem[16384];   // 32KB: xs dbuf + bt dbuf
    const int tid = threadIdx.x;
    // bijective XCD swizzle: nwg=1161, q=145, r=1 (XCD0 gets 146)
    const int bid = blockIdx.x;
    const int xcd = bid & 7, idx = bid >> 3;
    const int wgid = (xcd == 0) ? idx : 146 + (xcd-1)*145 + idx;
    const int m0 = (wgid / 9) * 128;   // m-major: XCD's wgid range spans all j
    const int j  = wgid % 9;
    const __bf16* xb = reinterpret_cast<const __bf16*>(xb_);
    const __bf16* wt = reinterpret_cast<const __bf16*>(Wt);
    __bf16* vtb = reinterpret_cast<__bf16*>(vtbuf);

    const int w = tid >> 6;
    const int lane = tid & 63;
    const int quad = lane >> 4, low = lane & 15;
    const int rg = lane >> 2, cg = lane & 3;   // 16 rows x 4 granules per chunk

    // wave w stages chunks w*2, w*2+1 (16 rows each) of both A and B
    int arow[2], brow[2], loff[2];
    #pragma unroll
    for (int i = 0; i < 2; ++i){
        int row = (w*2 + i)*16 + rg;
        int am = m0 + row; if (am > MTOT-1) am = MTOT-1;
        arow[i] = am;
        brow[i] = j*128 + row;          // < 1152 always
        loff[i] = (w*2 + i)*1024;       // bytes: 16 rows x 64B
    }

    // prologue: stage tile 0 into buffer 0 (xs at smem[0], bt at smem[8192])
    #pragma unroll
    for (int i = 0; i < 2; ++i){
        GLL16(xb + (size_t)arow[i]*EMBED + cg*8, (char*)smem + loff[i]);
        GLL16(wt + (size_t)brow[i]*EMBED + cg*8, (char*)(smem + 8192) + loff[i]);
    }
    __syncthreads();

    const int mh = w >> 1, nh = w & 1;
    const int mw0 = m0 + mh*64;

    f32x4 acc[4][4] = {};
    for (int kb = 0; kb < 12; ++kb){
        const int cur = kb & 1;
        const __bf16* xcur = smem + cur*4096;
        const __bf16* bcur = smem + 8192 + cur*4096;
        // issue tile k+1's loads into the alternate buffer (fly over compute)
        if (kb < 11){
            const int k1 = (kb+1)*32;
            __bf16* xnxt = smem + (cur^1)*4096;
            __bf16* bnxt = smem + 8192 + (cur^1)*4096;
            #pragma unroll
            for (int i = 0; i < 2; ++i){
                GLL16(xb + (size_t)arow[i]*EMBED + k1 + cg*8, (char*)xnxt + loff[i]);
                GLL16(wt + (size_t)brow[i]*EMBED + k1 + cg*8, (char*)bnxt + loff[i]);
            }
        }
        bf16x8 af[4], bfr[4];
        #pragma unroll
        for (int mt = 0; mt < 4; ++mt)
            af[mt] = *reinterpret_cast<const bf16x8*>(&xcur[(mh*64 + mt*16 + low)*32 + quad*8]);
        #pragma unroll
        for (int t = 0; t < 4; ++t)
            bfr[t] = *reinterpret_cast<const bf16x8*>(&bcur[(nh*64 + t*16 + low)*32 + quad*8]);
        #pragma unroll
        for (int t = 0; t < 4; ++t)
            #pragma unroll
            for (int mt = 0; mt < 4; ++mt)
                acc[mt][t] = MFMA_BF16(af[mt], bfr[t], acc[mt][t]);
        if (kb < 11) __syncthreads();   // drains vmcnt(0): tile k+1 landed
    }

    const int n64 = j*2 + nh;           // 0..17
    const int mat = n64 / 6;            // j-uniform (2j and 2j+1 share mat)
    const int h   = n64 % 6;

    if (mat == 2){
        // ---- V^T direct store via LDS transpose (block-uniform branch) ----
        __syncthreads();                // main-loop LDS reads done
        const int d8 = lane >> 3, sg = lane & 7;
        const int m0c = mw0 + sg*8;
        const int b0 = m0c / SEQ;
        const int s0 = m0c - b0*SEQ;
        const bool fast = (m0c + 7 < MTOT) && (s0 + 7 < SEQ);
        #pragma unroll
        for (int ph = 0; ph < 2; ++ph){
            if (mh == ph){
                __bf16* tl = smem + nh*4608;       // 64 x TSTR(66)
                #pragma unroll
                for (int mt = 0; mt < 4; ++mt)
                    #pragma unroll
                    for (int t = 0; t < 4; ++t)
                        #pragma unroll
                        for (int r = 0; r < 4; ++r)
                            tl[(mt*16 + quad*4 + r)*TSTR + t*16 + low] = f2bf(acc[mt][t][r]);
            }
            __syncthreads();
            if (mh == ph){
                __bf16* tl = smem + nh*4608;
                #pragma unroll
                for (int db = 0; db < 8; ++db){
                    const int d = db*8 + d8;
                    if (fast){
                        bf16x8 val;
                        #pragma unroll
                        for (int e = 0; e < 8; ++e) val[e] = tl[(sg*8+e)*TSTR + d];
                        *reinterpret_cast<bf16x8*>(
                            vtb + ((size_t)(b0*HEADS + h)*HD + d)*SEQP + s0) = val;
                    } else {
                        #pragma unroll
                        for (int e = 0; e < 8; ++e){
                            int m = m0c + e;
                            if (m < MTOT){
                                int bb = m / SEQ, ss = m - bb*SEQ;
                                vtb[((size_t)(bb*HEADS + h)*HD + d)*SEQP + ss] =
                                    tl[(sg*8+e)*TSTR + d];
                            }
                        }
                    }
                }
            }
            __syncthreads();
        }
    } else {
        __hip_bfloat16* ob = (mat == 0) ? qbuf : kbuf;
        const float qs_ = (mat == 0) ? 0.125f : 1.0f;
        #pragma unroll
        for (int mt = 0; mt < 4; ++mt)
            #pragma unroll
            for (int t = 0; t < 2; ++t)
                #pragma unroll
                for (int r = 0; r < 4; ++r){
                    int m = mw0 + mt*16 + quad*4 + r;
                    if (m < MTOT){
                        int b = m / SEQ, s = m % SEQ;
                        int f = t*16 + low;
                        float cv = cos_t[(s*HEADS + h)*NF + f];
                        float sv = sin_t[(s*HEADS + h)*NF + f];
                        float x1 = acc[mt][t][r];
                        float y1 = acc[mt][t+2][r];
                        size_t base = ((size_t)(b*HEADS + h)*SEQ + s)*HD;
                        ob[base + f]      = __float2bfloat16((x1*cv - y1*sv)*qs_);
                        ob[base + NF + f] = __float2bfloat16((x1*sv + y1*cv)*qs_);
                    }
                }
    }
}

// Flash attention, fixed-base softmax (no running max: scores bounded ~|5|).
// S^T = K.Q^T (qrow in-lane). PV = P.V via 16x16x16 MFMA with P in registers.
// T1: XCD-aware block swizzle (864 = 8 XCD x 108): each XCD owns 12 bh.
__global__ __launch_bounds__(256, 4) void attn_kernel(
    const __hip_bfloat16* __restrict__ qbuf,
    const __hip_bfloat16* __restrict__ kbuf,
    const __hip_bfloat16* __restrict__ vtbuf,
    __hip_bfloat16* __restrict__ aout)
{
    __shared__ __align__(16) __bf16 kls[64*LSTRIDE];    // [key][feat]
    __shared__ __align__(16) __bf16 vls[64*VSTR];       // [d][key], 136B stride
    const int tid  = threadIdx.x;
    const int w    = tid >> 6;
    const int lane = tid & 63;
    const int quad = lane >> 4, low = lane & 15;
    const int id = blockIdx.x;
    const int xcd = id & 7, sl = id >> 3;   // 108 slots per XCD
    const int bh = xcd*12 + sl/9;           // 12 bh pinned per XCD
    const int qt = sl % 9;
    const int b = bh / HEADS, h = bh % HEADS;
    const __bf16* qb = reinterpret_cast<const __bf16*>(qbuf);
    const __bf16* kb = reinterpret_cast<const __bf16*>(kbuf);
    const __bf16* vt = reinterpret_cast<const __bf16*>(vtbuf);
    const size_t base   = (size_t)bh * SEQ * HD;
    const size_t vtbase = (size_t)bh * HD * SEQP;
    const int q0 = qt*128 + w*32;

    int srow[2], sgk[2], soffk[2], soffv[2];
    #pragma unroll
    for (int i = 0; i < 2; ++i){
        int ch = tid + i*256;
        srow[i] = ch >> 3; sgk[i] = ch & 7;
        soffk[i] = srow[i]*LSTRIDE + sgk[i]*8;
        soffv[i] = srow[i]*VSTR    + sgk[i]*8;
    }

    bf16x8 bq[2][2];
    #pragma unroll
    for (int nt = 0; nt < 2; ++nt){
        int qs = q0 + nt*16 + low; if (qs > SEQ-1) qs = SEQ-1;
        #pragma unroll
        for (int ks = 0; ks < 2; ++ks)
            bq[nt][ks] = *reinterpret_cast<const bf16x8*>(qb + base + (size_t)qs*HD + ks*32 + quad*8);
    }

    bf16x8 kr[2], vr[2];
    #pragma unroll
    for (int i = 0; i < 2; ++i){
        int kk = srow[i]; if (kk > SEQ-1) kk = SEQ-1;
        kr[i] = *reinterpret_cast<const bf16x8*>(kb + base + (size_t)kk*HD + sgk[i]*8);
        vr[i] = *reinterpret_cast<const bf16x8*>(vt + vtbase + (size_t)srow[i]*SEQP + sgk[i]*8);
    }

    f32x4 o[2][4] = {};          // o[nt][dt]: row=q (quad*4+r), col=d (dt*16+low)
    float l_i[2] = {0.f, 0.f};

    for (int c = 0; c < NCHUNK; ++c){
        const int c0 = c*64;
        __syncthreads();
        #pragma unroll
        for (int i = 0; i < 2; ++i){
            *reinterpret_cast<bf16x8*>(&kls[soffk[i]]) = kr[i];
            bf16x4 vlo = __builtin_shufflevector(vr[i], vr[i], 0,1,2,3);
            bf16x4 vhi = __builtin_shufflevector(vr[i], vr[i], 4,5,6,7);
            *reinterpret_cast<bf16x4*>(&vls[soffv[i]])     = vlo;
            *reinterpret_cast<bf16x4*>(&vls[soffv[i] + 4]) = vhi;
        }
        __syncthreads();
        if (c + 1 < NCHUNK){
            const int c1 = c0 + 64;
            #pragma unroll
            for (int i = 0; i < 2; ++i){
                int kk = c1 + srow[i]; if (kk > SEQ-1) kk = SEQ-1;
                kr[i] = *reinterpret_cast<const bf16x8*>(kb + base + (size_t)kk*HD + sgk[i]*8);
                vr[i] = *reinterpret_cast<const bf16x8*>(vt + vtbase + (size_t)srow[i]*SEQP + c1 + sgk[i]*8);
            }
        }
        f32x4 st[4][2] = {};
        #pragma unroll
        for (int kt = 0; kt < 4; ++kt)
            #pragma unroll
            for (int ks = 0; ks < 2; ++ks){
                bf16x8 ak = *reinterpret_cast<const bf16x8*>(&kls[(kt*16 + low)*LSTRIDE + ks*32 + quad*8]);
                #pragma unroll
                for (int nt = 0; nt < 2; ++nt)
                    st[kt][nt] = MFMA_BF16(ak, bq[nt][ks], st[kt][nt]);
            }
        if (c0 + 64 > SEQ){
            #pragma unroll
            for (int kt = 0; kt < 4; ++kt)
                #pragma unroll
                for (int r = 0; r < 4; ++r){
                    int key = c0 + kt*16 + quad*4 + r;
                    if (key >= SEQ){ st[kt][0][r] = -1e30f; st[kt][1][r] = -1e30f; }
                }
        }
        // exp + in-lane l partial + pack P to bf16 A-fragments (in-register)
        s16x4 pa[4][2];
        #pragma unroll
        for (int nt = 0; nt < 2; ++nt)
            #pragma unroll
            for (int kt = 0; kt < 4; ++kt)
                #pragma unroll
                for (int r = 0; r < 4; ++r){
                    float p = __expf(st[kt][nt][r]);
                    l_i[nt] += p;
                    pa[kt][nt][r] = bfbits(p);
                }
        // O += P.V, A=P in-register, B=V from vls (conflict-free b64 reads)
        #pragma unroll
        for (int kt = 0; kt < 4; ++kt)
            #pragma unroll
            for (int dt = 0; dt < 4; ++dt){
                const s16x4 bv = *reinterpret_cast<const s16x4*>(&vls[(dt*16 + low)*VSTR + kt*16 + quad*4]);
                #pragma unroll
                for (int nt = 0; nt < 2; ++nt)
                    o[nt][dt] = MFMA16(pa[kt][nt], bv, o[nt][dt]);
            }
    }

    // reduce l across quads (lanes sharing 'low'), redistribute to output rows
    #pragma unroll
    for (int nt = 0; nt < 2; ++nt){
        l_i[nt] += __shfl_xor(l_i[nt], 16, 64);
        l_i[nt] += __shfl_xor(l_i[nt], 32, 64);
    }
    float lq[2][4];
    #pragma unroll
    for (int nt = 0; nt < 2; ++nt)
        #pragma unroll
        for (int r = 0; r < 4; ++r)
            lq[nt][r] = __shfl(l_i[nt], quad*4 + r, 64);

    #pragma unroll
    for (int nt = 0; nt < 2; ++nt)
        #pragma unroll
        for (int r = 0; r < 4; ++r){
            int s = q0 + nt*16 + quad*4 + r;
            if (s < SEQ){
                float inv = 1.0f / lq[nt][r];
                __hip_bfloat16* dst = aout + ((size_t)b*SEQ + s)*EMBED + h*HD;
                #pragma unroll
                for (int dt = 0; dt < 4; ++dt)
                    dst[dt*16 + low] = __float2bfloat16(o[nt][dt][r]*inv);
            }
        }
}

// out = attn @ Wo + bo. 64x128 tiles, 128 threads (2 waves x 64x64),
// grid (257, 3) = 771 blocks ~= 3.0/CU. m97-style double-buffered pipeline.
__global__ __launch_bounds__(128) void outproj_kernel(
    const __hip_bfloat16* __restrict__ a,
    const __hip_bfloat16* __restrict__ Wt,
    const float* __restrict__ bo,
    float* __restrict__ out)
{
    __shared__ __align__(16) __bf16 xs[2][64*32];
    __shared__ __align__(16) __bf16 bt[2][128*32];
    const int tid = threadIdx.x;          // 0..127
    const int m0 = blockIdx.x * 64;
    const int j  = blockIdx.y;
    const __bf16* ab = reinterpret_cast<const __bf16*>(a);
    const __bf16* wt = reinterpret_cast<const __bf16*>(Wt) + (size_t)3*EMBED*EMBED;

    const int w = tid >> 6;               // 0..1
    const int lane = tid & 63;
    const int quad = lane >> 4, low = lane & 15;
    const int rg = lane >> 2, cg = lane & 3;

    // A: 4 chunks of 16 rows; wave w stages chunks w*2, w*2+1
    int arow[2], aoff[2];
    #pragma unroll
    for (int i = 0; i < 2; ++i){
        int row = (w*2 + i)*16 + rg;
        int am = m0 + row; if (am > MTOT-1) am = MTOT-1;
        arow[i] = am;
        aoff[i] = (w*2 + i)*1024;
    }
    // B: 8 chunks of 16 rows; wave w stages chunks w*4 .. w*4+3
    int brow[4], boff[4];
    #pragma unroll
    for (int i = 0; i < 4; ++i){
        int row = (w*4 + i)*16 + rg;
        brow[i] = j*128 + row;
        boff[i] = (w*4 + i)*1024;
    }

    // prologue: stage tile 0 into buffer 0
    #pragma unroll
    for (int i = 0; i < 2; ++i)
        GLL16(ab + (size_t)arow[i]*EMBED + cg*8, (char*)xs[0] + aoff[i]);
    #pragma unroll
    for (int i = 0; i < 4; ++i)
        GLL16(wt + (size_t)brow[i]*EMBED + cg*8, (char*)bt[0] + boff[i]);
    __syncthreads();

    f32x4 acc[4][4] = {};
    for (int kb = 0; kb < 12; ++kb){
        const int cur = kb & 1;
        if (kb < 11){
            const int k1 = (kb+1)*32;
            #pragma unroll
            for (int i = 0; i < 2; ++i)
                GLL16(ab + (size_t)arow[i]*EMBED + k1 + cg*8, (char*)xs[cur^1] + aoff[i]);
            #pragma unroll
            for (int i = 0; i < 4; ++i)
                GLL16(wt + (size_t)brow[i]*EMBED + k1 + cg*8, (char*)bt[cur^1] + boff[i]);
        }
        bf16x8 af[4], bfr[4];
        #pragma unroll
        for (int mt = 0; mt < 4; ++mt)
            af[mt] = *reinterpret_cast<const bf16x8*>(&xs[cur][(mt*16 + low)*32 + quad*8]);
        #pragma unroll
        for (int t = 0; t < 4; ++t)
            bfr[t] = *reinterpret_cast<const bf16x8*>(&bt[cur][(w*64 + t*16 + low)*32 + quad*8]);
        #pragma unroll
        for (int t = 0; t < 4; ++t)
            #pragma unroll
            for (int mt = 0; mt < 4; ++mt)
                acc[mt][t] = MFMA_BF16(af[mt], bfr[t], acc[mt][t]);
        if (kb < 11) __syncthreads();
    }

    #pragma unroll
    for (int t = 0; t < 4; ++t){
        const int n = j*128 + w*64 + t*16 + low;
        const float bias = bo[n];
        #pragma unroll
        for (int mt = 0; mt < 4; ++mt)
            #pragma unroll
            for (int r = 0; r < 4; ++r){
                const int m = m0 + mt*16 + quad*4 + r;
                if (m < MTOT) out[(size_t)m*EMBED + n] = acc[mt][t][r] + bias;
            }
    }
}

extern "C" void kernel_launch(void* const* d_in, const int* in_sizes, int n_in,
                              void* d_out, int out_size, void* d_ws, size_t ws_size,
                              hipStream_t stream)
{
    const float* x  = (const float*)d_in[0];
    const float* Wq = (const float*)d_in[1];
    const float* Wk = (const float*)d_in[2];
    const float* Wv = (const float*)d_in[3];
    const float* Wo = (const float*)d_in[4];
    const float* bo = (const float*)d_in[5];
    float* out = (float*)d_out;

    // golden-ratio direction constants (exactly 10 cbrt iterations, as ref)
    double xd = 2.0;
    for (int it = 0; it < 10; ++it) xd = cbrt(1.0 + xd);
    float a1 = (float)(1.0 / xd);
    float a2 = a1 * a1;

    const size_t NE = (size_t)MTOT * EMBED;                 // 6,297,600
    const size_t VT = (size_t)BATCH*HEADS*HD*SEQP;          // padded V^T elems
    char* ws = (char*)d_ws;
    size_t off = 0;
    __hip_bfloat16* qbuf = (__hip_bfloat16*)(ws + off); off += 2*NE;
    __hip_bfloat16* kbuf = (__hip_bfloat16*)(ws + off); off += 2*NE;
    __hip_bfloat16* abuf = (__hip_bfloat16*)(ws + off); off += 2*NE;
    __hip_bfloat16* xbuf = (__hip_bfloat16*)(ws + off); off += 2*NE;
    __hip_bfloat16* vt   = (__hip_bfloat16*)(ws + off); off += 2*VT;
    __hip_bfloat16* Wt   = (__hip_bfloat16*)(ws + off); off += (size_t)4*EMBED*EMBED*2;
    float* cos_t = (float*)(ws + off); off += (size_t)SEQ*HEADS*NF*4;
    float* sin_t = (float*)(ws + off); off += (size_t)SEQ*HEADS*NF*4;

    prep_kernel<<<dim3(NB_X2B + NB_TW + NB_RT + NB_VF), dim3(256), 0, stream>>>(
        x, xbuf, Wq, Wk, Wv, Wo, Wt, cos_t, sin_t, vt, a1, a2);
    qkv_rope_kernel<<<dim3(1161), dim3(256), 0, stream>>>(xbuf, Wt, cos_t, sin_t, qbuf, kbuf, vt);
    attn_kernel<<<dim3(864), dim3(256), 0, stream>>>(qbuf, kbuf, vt, abuf);
    outproj_kernel<<<dim3((MTOT + 63)/64, 3), dim3(128), 0, stream>>>(abuf, Wt, bo, out);
}